// Round 8
// baseline (1011.406 us; speedup 1.0000x reference)
//
#include <hip/hip_runtime.h>
#include <hip/hip_bf16.h>

using bf16 = __hip_bfloat16;
typedef __bf16 bf16x8 __attribute__((ext_vector_type(8)));
typedef float f32x4 __attribute__((ext_vector_type(4)));

#define MROWS 100352   // 2048 windows * 49 tokens = 32*3136

__device__ __forceinline__ void async16(void* l, const void* g) {
    void* gg = const_cast<void*>(g);
    __builtin_amdgcn_global_load_lds((__attribute__((address_space(1))) void*)gg,
                                     (__attribute__((address_space(3))) void*)l, 16, 0, 0);
}

// stable tanh-approx GELU: max err vs exact erf-GELU ~7e-4, inf-safe
__device__ __forceinline__ float gelu_f(float x) {
    float u = 0.7978845608028654f * (x + 0.044715f * x * x * x);
    float e = __expf(2.0f * u);
    float t = 1.0f - 2.0f / (e + 1.0f);   // tanh(u); e=inf -> 1, e=0 -> -1
    return 0.5f * x * (1.0f + t);
}

__device__ __forceinline__ unsigned short bfu(float x) {
    bf16 b = __float2bfloat16(x);
    union { bf16 b; unsigned short u; } c; c.b = b; return c.u;
}

struct Cvt8 { const float* s[8]; bf16* d[8]; int n[8]; };

__global__ __launch_bounds__(256) void cvt8_k(Cvt8 c) {
    int seg = blockIdx.y;
    int i4 = (blockIdx.x * 256 + threadIdx.x) * 4;
    if (i4 < c.n[seg]) {
        float4 v = *(const float4*)(c.s[seg] + i4);
        bf16* d = c.d[seg] + i4;
        d[0] = __float2bfloat16(v.x);
        d[1] = __float2bfloat16(v.y);
        d[2] = __float2bfloat16(v.z);
        d[3] = __float2bfloat16(v.w);
    }
}

// LN1 + cyclic shift(-3,-3) + window partition. One wave per output row.
__global__ __launch_bounds__(256) void ln1_window_k(const float* __restrict__ x,
                                                    const float* __restrict__ g,
                                                    const float* __restrict__ bta,
                                                    bf16* __restrict__ ywin) {
    int wrow = blockIdx.x * 4 + (threadIdx.x >> 6);
    int lane = threadIdx.x & 63;
    int tok = wrow % 49, win = wrow / 49;
    int i = tok / 7, j = tok % 7;
    int wwi = win & 7, whi = (win >> 3) & 7, bi = win >> 6;
    int hs = (whi * 7 + i + 3) % 56;
    int ws_ = (wwi * 7 + j + 3) % 56;
    const float* xr = x + ((size_t)bi * 3136 + (size_t)hs * 56 + ws_) * 384;
    float v[6]; float s = 0.f, s2 = 0.f;
#pragma unroll
    for (int u = 0; u < 6; ++u) { float t = xr[lane + 64 * u]; v[u] = t; s += t; s2 += t * t; }
#pragma unroll
    for (int d = 1; d < 64; d <<= 1) { s += __shfl_xor(s, d); s2 += __shfl_xor(s2, d); }
    float mean = s * (1.0f / 384.0f);
    float var = s2 * (1.0f / 384.0f) - mean * mean;
    float rstd = rsqrtf(var + 1e-5f);
    bf16* yr = ywin + (size_t)wrow * 384;
#pragma unroll
    for (int u = 0; u < 6; ++u) {
        int c = lane + 64 * u;
        yr[c] = __float2bfloat16((v[u] - mean) * rstd * g[c] + bta[c]);
    }
}

// residual add (window-reverse + roll(+3,+3)) + LN2. x2 -> d_out (fp32), z -> bf16
__global__ __launch_bounds__(256) void resid_ln2_k(const float* __restrict__ x,
                                                   const bf16* __restrict__ proj,
                                                   const float* __restrict__ g,
                                                   const float* __restrict__ bta,
                                                   float* __restrict__ x2,
                                                   bf16* __restrict__ z) {
    int row = blockIdx.x * 4 + (threadIdx.x >> 6);
    int lane = threadIdx.x & 63;
    int bi = row / 3136; int hw = row % 3136;
    int h = hw / 56, w = hw % 56;
    int h2 = (h + 53) % 56, w2 = (w + 53) % 56;
    int prow = ((bi * 8 + h2 / 7) * 8 + w2 / 7) * 49 + (h2 % 7) * 7 + (w2 % 7);
    const float* xr = x + (size_t)row * 384;
    const bf16* pr = proj + (size_t)prow * 384;
    float* x2r = x2 + (size_t)row * 384;
    float v[6]; float s = 0.f, s2 = 0.f;
#pragma unroll
    for (int u = 0; u < 6; ++u) {
        int c = lane + 64 * u;
        float t = xr[c] + __bfloat162float(pr[c]);
        v[u] = t; s += t; s2 += t * t;
        x2r[c] = t;
    }
#pragma unroll
    for (int d = 1; d < 64; d <<= 1) { s += __shfl_xor(s, d); s2 += __shfl_xor(s2, d); }
    float mean = s * (1.0f / 384.0f);
    float var = s2 * (1.0f / 384.0f) - mean * mean;
    float rstd = rsqrtf(var + 1e-5f);
    bf16* zr = z + (size_t)row * 384;
#pragma unroll
    for (int u = 0; u < 6; ++u) {
        int c = lane + 64 * u;
        zr[c] = __float2bfloat16((v[u] - mean) * rstd * g[c] + bta[c]);
    }
}

// MFMA windowed attention: grid (2048 windows, 3 head-groups); 4 waves,
// one wave per head; one round per block.
__global__ __launch_bounds__(256) void attn_mfma_k(const bf16* __restrict__ qkv,
                                                   const float* __restrict__ rpbt,
                                                   bf16* __restrict__ o) {
    __shared__ __align__(16) __bf16 vt_s[4][32 * 72];   // V^T  [d][m], m padded to 64
    __shared__ __align__(16) __bf16 p_s[4][32 * 72];    // P half [n_loc][m]
    __shared__ float rpb_sh[676];                       // [ridx][4 heads of this group]
    const int win = blockIdx.x;
    const int r = blockIdx.y;
    const int wave = threadIdx.x >> 6, lane = threadIdx.x & 63;
    const int lo = lane & 15, hi = lane >> 4;
    const int whi = (win >> 3) & 7, wwi = win & 7;
    const bool bH = (whi == 7), bW = (wwi == 7);
    const bool boundary = bH || bW;
    __bf16* vt_w = vt_s[wave];
    __bf16* p_w = p_s[wave];
    const int h = r * 4 + wave;
    const bf16* qbase = qkv + (size_t)win * 49 * 1152 + h * 32;
    bf16x8 zf = {};

    for (int idx = threadIdx.x; idx < 676; idx += 256)
        rpb_sh[idx] = rpbt[(idx >> 2) * 12 + r * 4 + (idx & 3)];
    __syncthreads();

    // V -> LDS transposed; lane handles column m (write banks 2-way = free)
    {
        int m = lane;
        bf16x8 vrow[4];
#pragma unroll
        for (int d8 = 0; d8 < 4; ++d8)
            vrow[d8] = (m < 49) ? *(const bf16x8*)(qbase + (size_t)m * 1152 + 768 + d8 * 8) : zf;
#pragma unroll
        for (int d8 = 0; d8 < 4; ++d8)
#pragma unroll
            for (int e = 0; e < 8; ++e)
                vt_w[(d8 * 8 + e) * 72 + m] = vrow[d8][e];
    }
    // Q/K fragments directly from global (K-dim = 32 = one MFMA k-step)
    bf16x8 aq[4], bk[4];
    const int kq = hi * 8;
#pragma unroll
    for (int ta = 0; ta < 4; ++ta) {
        int n = ta * 16 + lo;
        aq[ta] = (n < 49) ? *(const bf16x8*)(qbase + (size_t)n * 1152 + kq) : zf;
        bk[ta] = (n < 49) ? *(const bf16x8*)(qbase + (size_t)n * 1152 + 384 + kq) : zf;
    }
    // S = Q K^T : acc[ta][tb], row n = 16ta+4hi+j, col m = 16tb+lo
    f32x4 acc[4][4] = {};
#pragma unroll
    for (int ta = 0; ta < 4; ++ta)
#pragma unroll
        for (int tb = 0; tb < 4; ++tb)
            acc[ta][tb] = __builtin_amdgcn_mfma_f32_16x16x32_bf16(aq[ta], bk[tb], acc[ta][tb], 0, 0, 0);
    // scale + rpb + shift-mask (in place)
    int i2[4], j2[4], rm[4];
#pragma unroll
    for (int tb = 0; tb < 4; ++tb) {
        int m = tb * 16 + lo;
        int mm = m < 49 ? m : 0;
        i2[tb] = mm / 7; j2[tb] = mm % 7;
        rm[tb] = (bH ? (i2[tb] < 4 ? 1 : 2) : 0) * 3 + (bW ? (j2[tb] < 4 ? 1 : 2) : 0);
    }
#pragma unroll
    for (int ta = 0; ta < 4; ++ta) {
#pragma unroll
        for (int j = 0; j < 4; ++j) {
            int n = ta * 16 + hi * 4 + j;
            int nn = n < 49 ? n : 0;
            int i1 = nn / 7, j1 = nn % 7;
            int rn = (bH ? (i1 < 4 ? 1 : 2) : 0) * 3 + (bW ? (j1 < 4 ? 1 : 2) : 0);
#pragma unroll
            for (int tb = 0; tb < 4; ++tb) {
                int m = tb * 16 + lo;
                float v;
                if (n < 49 && m < 49) {
                    v = acc[ta][tb][j] * 0.17677669529663687f
                        + rpb_sh[((i1 - i2[tb] + 6) * 13 + (j1 - j2[tb] + 6)) * 4 + wave];
                    if (boundary && rn != rm[tb]) v -= 100.0f;
                } else {
                    v = -1e30f;
                }
                acc[ta][tb][j] = v;
            }
        }
    }
    // V^T fragments (B-operand) hoisted once
    bf16x8 vb[2][2];
#pragma unroll
    for (int kb = 0; kb < 2; ++kb)
#pragma unroll
        for (int tb = 0; tb < 2; ++tb)
            vb[kb][tb] = *(const bf16x8*)(vt_w + (tb * 16 + lo) * 72 + kb * 32 + hi * 8);

    f32x4 oacc[4][2] = {};
    // two halves of 32 rows: softmax -> P half tile -> PV
#pragma unroll
    for (int half = 0; half < 2; ++half) {
#pragma unroll
        for (int tq = 0; tq < 2; ++tq) {
            int ta = half * 2 + tq;
#pragma unroll
            for (int j = 0; j < 4; ++j) {
                float mx = fmaxf(fmaxf(acc[ta][0][j], acc[ta][1][j]),
                                 fmaxf(acc[ta][2][j], acc[ta][3][j]));
                mx = fmaxf(mx, __shfl_xor(mx, 1));
                mx = fmaxf(mx, __shfl_xor(mx, 2));
                mx = fmaxf(mx, __shfl_xor(mx, 4));
                mx = fmaxf(mx, __shfl_xor(mx, 8));
                float e0 = __expf(acc[ta][0][j] - mx);
                float e1 = __expf(acc[ta][1][j] - mx);
                float e2 = __expf(acc[ta][2][j] - mx);
                float e3 = __expf(acc[ta][3][j] - mx);
                float sm = e0 + e1 + e2 + e3;
                sm += __shfl_xor(sm, 1);
                sm += __shfl_xor(sm, 2);
                sm += __shfl_xor(sm, 4);
                sm += __shfl_xor(sm, 8);
                float inv = 1.0f / sm;
                int nl = tq * 16 + hi * 4 + j;
                p_w[nl * 72 + lo]      = (__bf16)(e0 * inv);
                p_w[nl * 72 + 16 + lo] = (__bf16)(e1 * inv);
                p_w[nl * 72 + 32 + lo] = (__bf16)(e2 * inv);
                p_w[nl * 72 + 48 + lo] = (__bf16)(e3 * inv);
            }
        }
#pragma unroll
        for (int kb = 0; kb < 2; ++kb) {
#pragma unroll
            for (int tq = 0; tq < 2; ++tq) {
                bf16x8 pa = *(const bf16x8*)(p_w + (tq * 16 + lo) * 72 + kb * 32 + hi * 8);
#pragma unroll
                for (int tb = 0; tb < 2; ++tb)
                    oacc[half * 2 + tq][tb] =
                        __builtin_amdgcn_mfma_f32_16x16x32_bf16(pa, vb[kb][tb], oacc[half * 2 + tq][tb], 0, 0, 0);
            }
        }
    }
    bf16* obase = o + (size_t)win * 49 * 384 + h * 32;
#pragma unroll
    for (int ta = 0; ta < 4; ++ta) {
#pragma unroll
        for (int j = 0; j < 4; ++j) {
            int n = ta * 16 + hi * 4 + j;
            if (n < 49) {
#pragma unroll
                for (int tb = 0; tb < 2; ++tb)
                    obase[(size_t)n * 384 + tb * 16 + lo] = __float2bfloat16(oacc[ta][tb][j]);
            }
        }
    }
}

// C[M,N] = A[M,K] bf16 @ W[N,K]^T bf16.  Wave tile 64x64 (af[4] x bfr[4]
// -> 16 MFMA per 8 ds_read_b128: 0.5 reads/MFMA vs 0.75 at 64x32 -- the
// kernel is LDS-read-BW-bound). Block = 2 x NWN waves = 128M x (NWN*64)N.
// BK=64 single-buffer; slot-XOR (slot ^ row&7) both-sides: 0 conflicts.
// Swapped operands: lane holds 4 consecutive N cols -> packed 8B stores.
// XCD-chunked swizzle (nwg%8==0 always: 784%8==0).
template <int K, int NWN, int EPI>
__global__ __launch_bounds__(NWN * 128) void gemm_w64(const bf16* __restrict__ A,
                                                      const bf16* __restrict__ W,
                                                      const float* __restrict__ bias,
                                                      void* __restrict__ Cout,
                                                      int N) {
    constexpr int T = NWN * 128;
    constexpr int BN = NWN * 64;
    __shared__ __align__(16) bf16 lds_a[128 * 64];
    __shared__ __align__(16) bf16 lds_b[BN * 64];
    const int t = threadIdx.x;
    const int wave = t >> 6, lane = t & 63;
    const int wm = wave / NWN, wn = wave % NWN;
    const int fr = lane & 15, hi = lane >> 4;
    const int gdx = gridDim.x;
    int flat = blockIdx.y * gdx + blockIdx.x;
    int q = (gdx * gridDim.y) >> 3;
    int work = (flat & 7) * q + (flat >> 3);
    const int n0 = (work % gdx) * BN, m0 = (work / gdx) * 128;
    f32x4 acc[4][4] = {};
    for (int kt = 0; kt < K; kt += 64) {
        if (kt > 0) __syncthreads();
#pragma unroll
        for (int i = 0; i < 1024; i += T) {
            int u = i + t;
            if (u < 1024) {
                int row = u >> 3, slot = u & 7;
                int gslot = slot ^ (row & 7);
                async16((char*)lds_a + u * 16, A + (size_t)(m0 + row) * K + kt + gslot * 8);
            }
        }
#pragma unroll
        for (int i = 0; i < BN * 8; i += T) {
            int u = i + t;
            if (u < BN * 8) {
                int row = u >> 3, slot = u & 7;
                int gslot = slot ^ (row & 7);
                async16((char*)lds_b + u * 16, W + (size_t)(n0 + row) * K + kt + gslot * 8);
            }
        }
        __syncthreads();
#pragma unroll
        for (int ks = 0; ks < 2; ++ks) {
            bf16x8 af[4], bfr[4];
#pragma unroll
            for (int mi = 0; mi < 4; ++mi) {
                int row = wm * 64 + mi * 16 + fr;
                int slot = (ks * 4 + hi) ^ (row & 7);
                af[mi] = *(const bf16x8*)((const char*)lds_a + row * 128 + slot * 16);
            }
#pragma unroll
            for (int ni = 0; ni < 4; ++ni) {
                int row = wn * 64 + ni * 16 + fr;
                int slot = (ks * 4 + hi) ^ (row & 7);
                bfr[ni] = *(const bf16x8*)((const char*)lds_b + row * 128 + slot * 16);
            }
#pragma unroll
            for (int mi = 0; mi < 4; ++mi)
#pragma unroll
                for (int ni = 0; ni < 4; ++ni)
                    acc[mi][ni] = __builtin_amdgcn_mfma_f32_16x16x32_bf16(bfr[ni], af[mi], acc[mi][ni], 0, 0, 0);
        }
    }
#pragma unroll
    for (int mi = 0; mi < 4; ++mi) {
        int m = m0 + wm * 64 + mi * 16 + fr;
        size_t rowb = (size_t)m * N;
#pragma unroll
        for (int ni = 0; ni < 4; ++ni) {
            int nb = n0 + wn * 64 + ni * 16 + hi * 4;
            float v0 = acc[mi][ni][0], v1 = acc[mi][ni][1];
            float v2 = acc[mi][ni][2], v3 = acc[mi][ni][3];
            if (bias) {
                float4 b4 = *(const float4*)(bias + nb);
                v0 += b4.x; v1 += b4.y; v2 += b4.z; v3 += b4.w;
            }
            if (EPI == 1) { v0 = gelu_f(v0); v1 = gelu_f(v1); v2 = gelu_f(v2); v3 = gelu_f(v3); }
            if (EPI == 2) {
                float4* p = (float4*)((float*)Cout + rowb + nb);
                float4 o = *p;
                o.x += v0; o.y += v1; o.z += v2; o.w += v3;
                *p = o;
            } else {
                uint2 st;
                st.x = (unsigned)bfu(v0) | ((unsigned)bfu(v1) << 16);
                st.y = (unsigned)bfu(v2) | ((unsigned)bfu(v3) << 16);
                *(uint2*)((bf16*)Cout + rowb + nb) = st;
            }
        }
    }
}

extern "C" void kernel_launch(void* const* d_in, const int* in_sizes, int n_in,
                              void* d_out, int out_size, void* d_ws, size_t ws_size,
                              hipStream_t stream) {
    const float* x      = (const float*)d_in[0];
    const float* n1g    = (const float*)d_in[1];
    const float* n1b    = (const float*)d_in[2];
    const float* rpbt   = (const float*)d_in[3];
    const float* qkv_v  = (const float*)d_in[4];
    const float* qkv_u  = (const float*)d_in[5];
    const float* qkv_b  = (const float*)d_in[6];
    const float* proj_v = (const float*)d_in[7];
    const float* proj_u = (const float*)d_in[8];
    const float* proj_b = (const float*)d_in[9];
    const float* n2g    = (const float*)d_in[10];
    const float* n2b    = (const float*)d_in[11];
    const float* fc1_v  = (const float*)d_in[12];
    const float* fc1_u  = (const float*)d_in[13];
    const float* fc1_b  = (const float*)d_in[14];
    const float* fc2_v  = (const float*)d_in[15];
    const float* fc2_u  = (const float*)d_in[16];
    const float* fc2_b  = (const float*)d_in[17];

    char* ws = (char*)d_ws;
    bf16* wb = (bf16*)ws;
    bf16* w_qkv_v  = wb;
    bf16* w_qkv_u  = wb + 73728;
    bf16* w_proj_v = wb + 294912;
    bf16* w_proj_u = wb + 368640;
    bf16* w_fc1_v  = wb + 442368;
    bf16* w_fc1_u  = wb + 516096;
    bf16* w_fc2_v  = wb + 811008;
    bf16* w_fc2_u  = wb + 1105920;
    size_t off = (size_t)4 << 20;
    bf16* R1 = (bf16*)(ws + off); off += (size_t)MROWS * 1536 * 2;   // qkv / proj / mlp-hidden
    bf16* R2 = (bf16*)(ws + off); off += (size_t)MROWS * 384 * 2;    // ywin / o / z
    bf16* R3 = (bf16*)(ws + off);                                    // t1/t2/t3/t4 (M x 192)
    float* out = (float*)d_out;

    Cvt8 c;
    c.s[0] = qkv_v;  c.d[0] = w_qkv_v;  c.n[0] = 73728;
    c.s[1] = qkv_u;  c.d[1] = w_qkv_u;  c.n[1] = 221184;
    c.s[2] = proj_v; c.d[2] = w_proj_v; c.n[2] = 73728;
    c.s[3] = proj_u; c.d[3] = w_proj_u; c.n[3] = 73728;
    c.s[4] = fc1_v;  c.d[4] = w_fc1_v;  c.n[4] = 73728;
    c.s[5] = fc1_u;  c.d[5] = w_fc1_u;  c.n[5] = 294912;
    c.s[6] = fc2_v;  c.d[6] = w_fc2_v;  c.n[6] = 294912;
    c.s[7] = fc2_u;  c.d[7] = w_fc2_u;  c.n[7] = 73728;
    cvt8_k<<<dim3(288, 8), 256, 0, stream>>>(c);

    ln1_window_k<<<MROWS / 4, 256, 0, stream>>>(x, n1g, n1b, R2);
    gemm_w64<384, 3, 0><<<dim3(1, 784), 384, 0, stream>>>(R2, w_qkv_v, nullptr, R3, 192);
    gemm_w64<192, 2, 0><<<dim3(9, 784), 256, 0, stream>>>(R3, w_qkv_u, qkv_b, R1, 1152);
    attn_mfma_k<<<dim3(2048, 3), 256, 0, stream>>>(R1, rpbt, R2);
    gemm_w64<384, 3, 0><<<dim3(1, 784), 384, 0, stream>>>(R2, w_proj_v, nullptr, R3, 192);
    gemm_w64<192, 2, 0><<<dim3(3, 784), 256, 0, stream>>>(R3, w_proj_u, proj_b, R1, 384);
    resid_ln2_k<<<MROWS / 4, 256, 0, stream>>>(x, R1, n2g, n2b, out, R2);
    gemm_w64<384, 3, 0><<<dim3(1, 784), 384, 0, stream>>>(R2, w_fc1_v, nullptr, R3, 192);
    gemm_w64<192, 2, 1><<<dim3(12, 784), 256, 0, stream>>>(R3, w_fc1_u, fc1_b, R1, 1536);
    gemm_w64<1536, 3, 0><<<dim3(1, 784), 384, 0, stream>>>(R1, w_fc2_v, nullptr, R3, 192);
    gemm_w64<192, 2, 2><<<dim3(3, 784), 256, 0, stream>>>(R3, w_fc2_u, fc2_b, out, 384);
}

// Round 9
// 926.417 us; speedup vs baseline: 1.0917x; 1.0917x over previous
//
#include <hip/hip_runtime.h>
#include <hip/hip_bf16.h>

using bf16 = __hip_bfloat16;
typedef __bf16 bf16x8 __attribute__((ext_vector_type(8)));
typedef float f32x4 __attribute__((ext_vector_type(4)));

#define MROWS 100352   // 2048 windows * 49 tokens = 32*3136

__device__ __forceinline__ void async16(void* l, const void* g) {
    void* gg = const_cast<void*>(g);
    __builtin_amdgcn_global_load_lds((__attribute__((address_space(1))) void*)gg,
                                     (__attribute__((address_space(3))) void*)l, 16, 0, 0);
}

// stable tanh-approx GELU: max err vs exact erf-GELU ~7e-4, inf-safe
__device__ __forceinline__ float gelu_f(float x) {
    float u = 0.7978845608028654f * (x + 0.044715f * x * x * x);
    float e = __expf(2.0f * u);
    float t = 1.0f - 2.0f / (e + 1.0f);   // tanh(u); e=inf -> 1, e=0 -> -1
    return 0.5f * x * (1.0f + t);
}

__device__ __forceinline__ unsigned short bfu(float x) {
    bf16 b = __float2bfloat16(x);
    union { bf16 b; unsigned short u; } c; c.b = b; return c.u;
}

struct Cvt8 { const float* s[8]; bf16* d[8]; int n[8]; };

__global__ __launch_bounds__(256) void cvt8_k(Cvt8 c) {
    int seg = blockIdx.y;
    int i4 = (blockIdx.x * 256 + threadIdx.x) * 4;
    if (i4 < c.n[seg]) {
        float4 v = *(const float4*)(c.s[seg] + i4);
        bf16* d = c.d[seg] + i4;
        d[0] = __float2bfloat16(v.x);
        d[1] = __float2bfloat16(v.y);
        d[2] = __float2bfloat16(v.z);
        d[3] = __float2bfloat16(v.w);
    }
}

// LN1 + cyclic shift(-3,-3) + window partition. One wave per output row.
__global__ __launch_bounds__(256) void ln1_window_k(const float* __restrict__ x,
                                                    const float* __restrict__ g,
                                                    const float* __restrict__ bta,
                                                    bf16* __restrict__ ywin) {
    int wrow = blockIdx.x * 4 + (threadIdx.x >> 6);
    int lane = threadIdx.x & 63;
    int tok = wrow % 49, win = wrow / 49;
    int i = tok / 7, j = tok % 7;
    int wwi = win & 7, whi = (win >> 3) & 7, bi = win >> 6;
    int hs = (whi * 7 + i + 3) % 56;
    int ws_ = (wwi * 7 + j + 3) % 56;
    const float* xr = x + ((size_t)bi * 3136 + (size_t)hs * 56 + ws_) * 384;
    float v[6]; float s = 0.f, s2 = 0.f;
#pragma unroll
    for (int u = 0; u < 6; ++u) { float t = xr[lane + 64 * u]; v[u] = t; s += t; s2 += t * t; }
#pragma unroll
    for (int d = 1; d < 64; d <<= 1) { s += __shfl_xor(s, d); s2 += __shfl_xor(s2, d); }
    float mean = s * (1.0f / 384.0f);
    float var = s2 * (1.0f / 384.0f) - mean * mean;
    float rstd = rsqrtf(var + 1e-5f);
    bf16* yr = ywin + (size_t)wrow * 384;
#pragma unroll
    for (int u = 0; u < 6; ++u) {
        int c = lane + 64 * u;
        yr[c] = __float2bfloat16((v[u] - mean) * rstd * g[c] + bta[c]);
    }
}

// residual add (window-reverse + roll(+3,+3)) + LN2. x2 -> d_out (fp32), z -> bf16
__global__ __launch_bounds__(256) void resid_ln2_k(const float* __restrict__ x,
                                                   const bf16* __restrict__ proj,
                                                   const float* __restrict__ g,
                                                   const float* __restrict__ bta,
                                                   float* __restrict__ x2,
                                                   bf16* __restrict__ z) {
    int row = blockIdx.x * 4 + (threadIdx.x >> 6);
    int lane = threadIdx.x & 63;
    int bi = row / 3136; int hw = row % 3136;
    int h = hw / 56, w = hw % 56;
    int h2 = (h + 53) % 56, w2 = (w + 53) % 56;
    int prow = ((bi * 8 + h2 / 7) * 8 + w2 / 7) * 49 + (h2 % 7) * 7 + (w2 % 7);
    const float* xr = x + (size_t)row * 384;
    const bf16* pr = proj + (size_t)prow * 384;
    float* x2r = x2 + (size_t)row * 384;
    float v[6]; float s = 0.f, s2 = 0.f;
#pragma unroll
    for (int u = 0; u < 6; ++u) {
        int c = lane + 64 * u;
        float t = xr[c] + __bfloat162float(pr[c]);
        v[u] = t; s += t; s2 += t * t;
        x2r[c] = t;
    }
#pragma unroll
    for (int d = 1; d < 64; d <<= 1) { s += __shfl_xor(s, d); s2 += __shfl_xor(s2, d); }
    float mean = s * (1.0f / 384.0f);
    float var = s2 * (1.0f / 384.0f) - mean * mean;
    float rstd = rsqrtf(var + 1e-5f);
    bf16* zr = z + (size_t)row * 384;
#pragma unroll
    for (int u = 0; u < 6; ++u) {
        int c = lane + 64 * u;
        zr[c] = __float2bfloat16((v[u] - mean) * rstd * g[c] + bta[c]);
    }
}

// MFMA windowed attention: grid (2048 windows, 3 head-groups); 4 waves,
// one wave per head; one round per block.
__global__ __launch_bounds__(256) void attn_mfma_k(const bf16* __restrict__ qkv,
                                                   const float* __restrict__ rpbt,
                                                   bf16* __restrict__ o) {
    __shared__ __align__(16) __bf16 vt_s[4][32 * 72];   // V^T  [d][m], m padded to 64
    __shared__ __align__(16) __bf16 p_s[4][32 * 72];    // P half [n_loc][m]
    __shared__ float rpb_sh[676];                       // [ridx][4 heads of this group]
    const int win = blockIdx.x;
    const int r = blockIdx.y;
    const int wave = threadIdx.x >> 6, lane = threadIdx.x & 63;
    const int lo = lane & 15, hi = lane >> 4;
    const int whi = (win >> 3) & 7, wwi = win & 7;
    const bool bH = (whi == 7), bW = (wwi == 7);
    const bool boundary = bH || bW;
    __bf16* vt_w = vt_s[wave];
    __bf16* p_w = p_s[wave];
    const int h = r * 4 + wave;
    const bf16* qbase = qkv + (size_t)win * 49 * 1152 + h * 32;
    bf16x8 zf = {};

    for (int idx = threadIdx.x; idx < 676; idx += 256)
        rpb_sh[idx] = rpbt[(idx >> 2) * 12 + r * 4 + (idx & 3)];
    __syncthreads();

    // V -> LDS transposed; lane handles column m (write banks 2-way = free)
    {
        int m = lane;
        bf16x8 vrow[4];
#pragma unroll
        for (int d8 = 0; d8 < 4; ++d8)
            vrow[d8] = (m < 49) ? *(const bf16x8*)(qbase + (size_t)m * 1152 + 768 + d8 * 8) : zf;
#pragma unroll
        for (int d8 = 0; d8 < 4; ++d8)
#pragma unroll
            for (int e = 0; e < 8; ++e)
                vt_w[(d8 * 8 + e) * 72 + m] = vrow[d8][e];
    }
    // Q/K fragments directly from global (K-dim = 32 = one MFMA k-step)
    bf16x8 aq[4], bk[4];
    const int kq = hi * 8;
#pragma unroll
    for (int ta = 0; ta < 4; ++ta) {
        int n = ta * 16 + lo;
        aq[ta] = (n < 49) ? *(const bf16x8*)(qbase + (size_t)n * 1152 + kq) : zf;
        bk[ta] = (n < 49) ? *(const bf16x8*)(qbase + (size_t)n * 1152 + 384 + kq) : zf;
    }
    // S = Q K^T : acc[ta][tb], row n = 16ta+4hi+j, col m = 16tb+lo
    f32x4 acc[4][4] = {};
#pragma unroll
    for (int ta = 0; ta < 4; ++ta)
#pragma unroll
        for (int tb = 0; tb < 4; ++tb)
            acc[ta][tb] = __builtin_amdgcn_mfma_f32_16x16x32_bf16(aq[ta], bk[tb], acc[ta][tb], 0, 0, 0);
    // scale + rpb + shift-mask (in place)
    int i2[4], j2[4], rm[4];
#pragma unroll
    for (int tb = 0; tb < 4; ++tb) {
        int m = tb * 16 + lo;
        int mm = m < 49 ? m : 0;
        i2[tb] = mm / 7; j2[tb] = mm % 7;
        rm[tb] = (bH ? (i2[tb] < 4 ? 1 : 2) : 0) * 3 + (bW ? (j2[tb] < 4 ? 1 : 2) : 0);
    }
#pragma unroll
    for (int ta = 0; ta < 4; ++ta) {
#pragma unroll
        for (int j = 0; j < 4; ++j) {
            int n = ta * 16 + hi * 4 + j;
            int nn = n < 49 ? n : 0;
            int i1 = nn / 7, j1 = nn % 7;
            int rn = (bH ? (i1 < 4 ? 1 : 2) : 0) * 3 + (bW ? (j1 < 4 ? 1 : 2) : 0);
#pragma unroll
            for (int tb = 0; tb < 4; ++tb) {
                int m = tb * 16 + lo;
                float v;
                if (n < 49 && m < 49) {
                    v = acc[ta][tb][j] * 0.17677669529663687f
                        + rpb_sh[((i1 - i2[tb] + 6) * 13 + (j1 - j2[tb] + 6)) * 4 + wave];
                    if (boundary && rn != rm[tb]) v -= 100.0f;
                } else {
                    v = -1e30f;
                }
                acc[ta][tb][j] = v;
            }
        }
    }
    // V^T fragments (B-operand) hoisted once
    bf16x8 vb[2][2];
#pragma unroll
    for (int kb = 0; kb < 2; ++kb)
#pragma unroll
        for (int tb = 0; tb < 2; ++tb)
            vb[kb][tb] = *(const bf16x8*)(vt_w + (tb * 16 + lo) * 72 + kb * 32 + hi * 8);

    f32x4 oacc[4][2] = {};
    // two halves of 32 rows: softmax -> P half tile -> PV
#pragma unroll
    for (int half = 0; half < 2; ++half) {
#pragma unroll
        for (int tq = 0; tq < 2; ++tq) {
            int ta = half * 2 + tq;
#pragma unroll
            for (int j = 0; j < 4; ++j) {
                float mx = fmaxf(fmaxf(acc[ta][0][j], acc[ta][1][j]),
                                 fmaxf(acc[ta][2][j], acc[ta][3][j]));
                mx = fmaxf(mx, __shfl_xor(mx, 1));
                mx = fmaxf(mx, __shfl_xor(mx, 2));
                mx = fmaxf(mx, __shfl_xor(mx, 4));
                mx = fmaxf(mx, __shfl_xor(mx, 8));
                float e0 = __expf(acc[ta][0][j] - mx);
                float e1 = __expf(acc[ta][1][j] - mx);
                float e2 = __expf(acc[ta][2][j] - mx);
                float e3 = __expf(acc[ta][3][j] - mx);
                float sm = e0 + e1 + e2 + e3;
                sm += __shfl_xor(sm, 1);
                sm += __shfl_xor(sm, 2);
                sm += __shfl_xor(sm, 4);
                sm += __shfl_xor(sm, 8);
                float inv = 1.0f / sm;
                int nl = tq * 16 + hi * 4 + j;
                p_w[nl * 72 + lo]      = (__bf16)(e0 * inv);
                p_w[nl * 72 + 16 + lo] = (__bf16)(e1 * inv);
                p_w[nl * 72 + 32 + lo] = (__bf16)(e2 * inv);
                p_w[nl * 72 + 48 + lo] = (__bf16)(e3 * inv);
            }
        }
#pragma unroll
        for (int kb = 0; kb < 2; ++kb) {
#pragma unroll
            for (int tq = 0; tq < 2; ++tq) {
                bf16x8 pa = *(const bf16x8*)(p_w + (tq * 16 + lo) * 72 + kb * 32 + hi * 8);
#pragma unroll
                for (int tb = 0; tb < 2; ++tb)
                    oacc[half * 2 + tq][tb] =
                        __builtin_amdgcn_mfma_f32_16x16x32_bf16(pa, vb[kb][tb], oacc[half * 2 + tq][tb], 0, 0, 0);
            }
        }
    }
    bf16* obase = o + (size_t)win * 49 * 384 + h * 32;
#pragma unroll
    for (int ta = 0; ta < 4; ++ta) {
#pragma unroll
        for (int j = 0; j < 4; ++j) {
            int n = ta * 16 + hi * 4 + j;
            if (n < 49) {
#pragma unroll
                for (int tb = 0; tb < 2; ++tb)
                    obase[(size_t)n * 384 + tb * 16 + lo] = __float2bfloat16(oacc[ta][tb][j]);
            }
        }
    }
}

// C[M,N] = A[M,K] bf16 @ W[N,K]^T bf16.  BK=64, 24 KB LDS -> 6 blocks/CU.
// Swapped operands; packed uint2 stores; XCD-chunked swizzle (nwg%8==0).
// Used for the N=192 V-GEMMs.
template <int K, int EPI>
__global__ __launch_bounds__(256) void gemm_bt(const bf16* __restrict__ A,
                                               const bf16* __restrict__ W,
                                               const float* __restrict__ bias,
                                               void* __restrict__ Cout,
                                               int N) {
    __shared__ __align__(16) bf16 lds_a[128 * 64];
    __shared__ __align__(16) bf16 lds_b[64 * 64];
    const int t = threadIdx.x;
    const int wave = t >> 6, lane = t & 63;
    const int gdx = gridDim.x;
    int flat = blockIdx.y * gdx + blockIdx.x;
    int q = (gdx * gridDim.y) >> 3;
    int work = (flat & 7) * q + (flat >> 3);
    const int n0 = (work % gdx) * 64, m0 = (work / gdx) * 128;
    const int wm = wave >> 1, wn = wave & 1;
    const int fr = lane & 15, hi = lane >> 4;
    f32x4 acc[4][2] = {};
    for (int kt = 0; kt < K; kt += 64) {
        if (kt > 0) __syncthreads();
#pragma unroll
        for (int i = 0; i < 4; ++i) {
            int u = i * 256 + t;
            int row = u >> 3, slot = u & 7;
            int gslot = slot ^ (row & 7);
            async16((char*)lds_a + u * 16, A + (size_t)(m0 + row) * K + kt + gslot * 8);
        }
#pragma unroll
        for (int i = 0; i < 2; ++i) {
            int u = i * 256 + t;
            int row = u >> 3, slot = u & 7;
            int gslot = slot ^ (row & 7);
            async16((char*)lds_b + u * 16, W + (size_t)(n0 + row) * K + kt + gslot * 8);
        }
        __syncthreads();
#pragma unroll
        for (int ks = 0; ks < 2; ++ks) {
            bf16x8 af[4], bfr[2];
#pragma unroll
            for (int mi = 0; mi < 4; ++mi) {
                int row = wm * 64 + mi * 16 + fr;
                int slot = (ks * 4 + hi) ^ (row & 7);
                af[mi] = *(const bf16x8*)((const char*)lds_a + row * 128 + slot * 16);
            }
#pragma unroll
            for (int ni = 0; ni < 2; ++ni) {
                int row = wn * 32 + ni * 16 + fr;
                int slot = (ks * 4 + hi) ^ (row & 7);
                bfr[ni] = *(const bf16x8*)((const char*)lds_b + row * 128 + slot * 16);
            }
#pragma unroll
            for (int mi = 0; mi < 4; ++mi)
#pragma unroll
                for (int ni = 0; ni < 2; ++ni)
                    acc[mi][ni] = __builtin_amdgcn_mfma_f32_16x16x32_bf16(bfr[ni], af[mi], acc[mi][ni], 0, 0, 0);
        }
    }
    const int rq4 = hi * 4;
#pragma unroll
    for (int mi = 0; mi < 4; ++mi) {
        int m = m0 + wm * 64 + mi * 16 + fr;
        size_t rowb = (size_t)m * N;
#pragma unroll
        for (int ni = 0; ni < 2; ++ni) {
            int nb = n0 + wn * 32 + ni * 16 + rq4;
            float v0 = acc[mi][ni][0], v1 = acc[mi][ni][1];
            float v2 = acc[mi][ni][2], v3 = acc[mi][ni][3];
            if (bias) {
                float4 b4 = *(const float4*)(bias + nb);
                v0 += b4.x; v1 += b4.y; v2 += b4.z; v3 += b4.w;
            }
            if (EPI == 1) { v0 = gelu_f(v0); v1 = gelu_f(v1); v2 = gelu_f(v2); v3 = gelu_f(v3); }
            if (EPI == 2) {
                float4* p = (float4*)((float*)Cout + rowb + nb);
                float4 o = *p;
                o.x += v0; o.y += v1; o.z += v2; o.w += v3;
                *p = o;
            } else {
                uint2 st;
                st.x = (unsigned)bfu(v0) | ((unsigned)bfu(v1) << 16);
                st.y = (unsigned)bfu(v2) | ((unsigned)bfu(v3) << 16);
                *(uint2*)((bf16*)Cout + rowb + nb) = st;
            }
        }
    }
}

// Persistent-B register GEMM for the K=192 U-GEMMs (W is small and L2-hot).
// Each wave holds B fragments for its 32 n-cols x full K in 48 VGPRs (loaded
// once); block loops over MT=8 m-tiles of 64 rows, double-buffered A in LDS.
// Prefetch of tile t+1 is issued BEFORE compute of tile t, so the barrier's
// vmcnt drain is covered by 48 MFMA + epilogue (~500+ cy). One barrier/tile.
// Epilogue: swapped layout -> lane holds 4 consecutive n at fixed m.
template <int N, int EPI>
__global__ __launch_bounds__(256) void gemm_pb(const bf16* __restrict__ A,
                                               const bf16* __restrict__ W,
                                               const float* __restrict__ bias,
                                               void* __restrict__ Cout) {
    constexpr int K = 192;
    constexpr int MT = 8;
    __shared__ __align__(16) bf16 lds_a[2][64 * 192];
    const int t = threadIdx.x;
    const int wv = t >> 6, lane = t & 63;
    const int fr = lane & 15, hi = lane >> 4;
    const int gdx = gridDim.x;
    // bijective XCD-chunk swizzle (nwg may not be %8==0)
    int nwg = gdx * gridDim.y;
    int flat = blockIdx.y * gdx + blockIdx.x;
    int q = nwg >> 3, r = nwg & 7;
    int xcd = flat & 7, sub = flat >> 3;
    int work = (xcd < r ? xcd * (q + 1) : r * (q + 1) + (xcd - r) * q) + sub;
    const int n0 = (work % gdx) * 128;
    const int mstrip = (work / gdx) * (MT * 64);

    // B fragments: 32 n-cols per wave, full K (12 x 16B per lane, L2-hot)
    bf16x8 breg[6][2];
#pragma unroll
    for (int kk = 0; kk < 6; ++kk)
#pragma unroll
        for (int nn = 0; nn < 2; ++nn)
            breg[kk][nn] = *(const bf16x8*)(W + (size_t)(n0 + wv * 32 + nn * 16 + fr) * K + kk * 32 + hi * 8);

    bf16* cur = (bf16*)lds_a[0];
    bf16* nxt = (bf16*)lds_a[1];
    // prologue: stage m-tile 0 (row stride 192 elems = 24 slots of 16B,
    // slot-XOR (slot ^ row&7) both-sides -- proven 0-conflict at BK=192)
#pragma unroll
    for (int i = 0; i < 6; ++i) {
        int u = i * 256 + t;
        int row = u / 24, slot = u % 24;
        int gslot = slot ^ (row & 7);
        async16((char*)cur + u * 16, A + (size_t)(mstrip + row) * K + gslot * 8);
    }
    __syncthreads();
    for (int mt = 0; mt < MT; ++mt) {
        if (mt + 1 < MT) {
#pragma unroll
            for (int i = 0; i < 6; ++i) {
                int u = i * 256 + t;
                int row = u / 24, slot = u % 24;
                int gslot = slot ^ (row & 7);
                async16((char*)nxt + u * 16,
                        A + (size_t)(mstrip + (mt + 1) * 64 + row) * K + gslot * 8);
            }
        }
        f32x4 acc[4][2] = {};
#pragma unroll
        for (int kk = 0; kk < 6; ++kk) {
            bf16x8 af[4];
#pragma unroll
            for (int mi = 0; mi < 4; ++mi) {
                int row = mi * 16 + fr;
                int slot = (kk * 4 + hi) ^ (row & 7);
                af[mi] = *(const bf16x8*)((const char*)cur + row * 384 + slot * 16);
            }
#pragma unroll
            for (int mi = 0; mi < 4; ++mi)
#pragma unroll
                for (int nn = 0; nn < 2; ++nn)
                    acc[mi][nn] = __builtin_amdgcn_mfma_f32_16x16x32_bf16(breg[kk][nn], af[mi], acc[mi][nn], 0, 0, 0);
        }
        // epilogue for this m-tile
#pragma unroll
        for (int mi = 0; mi < 4; ++mi) {
            int m = mstrip + mt * 64 + mi * 16 + fr;
            size_t rowb = (size_t)m * N;
#pragma unroll
            for (int nn = 0; nn < 2; ++nn) {
                int nb = n0 + wv * 32 + nn * 16 + hi * 4;
                float v0 = acc[mi][nn][0], v1 = acc[mi][nn][1];
                float v2 = acc[mi][nn][2], v3 = acc[mi][nn][3];
                if (bias) {
                    float4 b4 = *(const float4*)(bias + nb);
                    v0 += b4.x; v1 += b4.y; v2 += b4.z; v3 += b4.w;
                }
                if (EPI == 1) { v0 = gelu_f(v0); v1 = gelu_f(v1); v2 = gelu_f(v2); v3 = gelu_f(v3); }
                if (EPI == 2) {
                    float4* p = (float4*)((float*)Cout + rowb + nb);
                    float4 o = *p;
                    o.x += v0; o.y += v1; o.z += v2; o.w += v3;
                    *p = o;
                } else {
                    uint2 st;
                    st.x = (unsigned)bfu(v0) | ((unsigned)bfu(v1) << 16);
                    st.y = (unsigned)bfu(v2) | ((unsigned)bfu(v3) << 16);
                    *(uint2*)((bf16*)Cout + rowb + nb) = st;
                }
            }
        }
        __syncthreads();
        bf16* tmp = cur; cur = nxt; nxt = tmp;
    }
}

extern "C" void kernel_launch(void* const* d_in, const int* in_sizes, int n_in,
                              void* d_out, int out_size, void* d_ws, size_t ws_size,
                              hipStream_t stream) {
    const float* x      = (const float*)d_in[0];
    const float* n1g    = (const float*)d_in[1];
    const float* n1b    = (const float*)d_in[2];
    const float* rpbt   = (const float*)d_in[3];
    const float* qkv_v  = (const float*)d_in[4];
    const float* qkv_u  = (const float*)d_in[5];
    const float* qkv_b  = (const float*)d_in[6];
    const float* proj_v = (const float*)d_in[7];
    const float* proj_u = (const float*)d_in[8];
    const float* proj_b = (const float*)d_in[9];
    const float* n2g    = (const float*)d_in[10];
    const float* n2b    = (const float*)d_in[11];
    const float* fc1_v  = (const float*)d_in[12];
    const float* fc1_u  = (const float*)d_in[13];
    const float* fc1_b  = (const float*)d_in[14];
    const float* fc2_v  = (const float*)d_in[15];
    const float* fc2_u  = (const float*)d_in[16];
    const float* fc2_b  = (const float*)d_in[17];

    char* ws = (char*)d_ws;
    bf16* wb = (bf16*)ws;
    bf16* w_qkv_v  = wb;
    bf16* w_qkv_u  = wb + 73728;
    bf16* w_proj_v = wb + 294912;
    bf16* w_proj_u = wb + 368640;
    bf16* w_fc1_v  = wb + 442368;
    bf16* w_fc1_u  = wb + 516096;
    bf16* w_fc2_v  = wb + 811008;
    bf16* w_fc2_u  = wb + 1105920;
    size_t off = (size_t)4 << 20;
    bf16* R1 = (bf16*)(ws + off); off += (size_t)MROWS * 1536 * 2;   // qkv / proj / mlp-hidden
    bf16* R2 = (bf16*)(ws + off); off += (size_t)MROWS * 384 * 2;    // ywin / o / z
    bf16* R3 = (bf16*)(ws + off);                                    // t1/t2/t3/t4 (M x 192)
    float* out = (float*)d_out;

    Cvt8 c;
    c.s[0] = qkv_v;  c.d[0] = w_qkv_v;  c.n[0] = 73728;
    c.s[1] = qkv_u;  c.d[1] = w_qkv_u;  c.n[1] = 221184;
    c.s[2] = proj_v; c.d[2] = w_proj_v; c.n[2] = 73728;
    c.s[3] = proj_u; c.d[3] = w_proj_u; c.n[3] = 73728;
    c.s[4] = fc1_v;  c.d[4] = w_fc1_v;  c.n[4] = 73728;
    c.s[5] = fc1_u;  c.d[5] = w_fc1_u;  c.n[5] = 294912;
    c.s[6] = fc2_v;  c.d[6] = w_fc2_v;  c.n[6] = 294912;
    c.s[7] = fc2_u;  c.d[7] = w_fc2_u;  c.n[7] = 73728;
    cvt8_k<<<dim3(288, 8), 256, 0, stream>>>(c);

    ln1_window_k<<<MROWS / 4, 256, 0, stream>>>(x, n1g, n1b, R2);
    gemm_bt<384, 0><<<dim3(3, 784), 256, 0, stream>>>(R2, w_qkv_v, nullptr, R3, 192);
    gemm_pb<1152, 0><<<dim3(9, 196), 256, 0, stream>>>(R3, w_qkv_u, qkv_b, R1);
    attn_mfma_k<<<dim3(2048, 3), 256, 0, stream>>>(R1, rpbt, R2);
    gemm_bt<384, 0><<<dim3(3, 784), 256, 0, stream>>>(R2, w_proj_v, nullptr, R3, 192);
    gemm_pb<384, 0><<<dim3(3, 196), 256, 0, stream>>>(R3, w_proj_u, proj_b, R1);
    resid_ln2_k<<<MROWS / 4, 256, 0, stream>>>(x, R1, n2g, n2b, out, R2);
    gemm_bt<384, 0><<<dim3(3, 784), 256, 0, stream>>>(R2, w_fc1_v, nullptr, R3, 192);
    gemm_pb<1536, 1><<<dim3(12, 196), 256, 0, stream>>>(R3, w_fc1_u, fc1_b, R1);
    gemm_bt<1536, 0><<<dim3(3, 784), 256, 0, stream>>>(R1, w_fc2_v, nullptr, R3, 192);
    gemm_pb<384, 2><<<dim3(3, 196), 256, 0, stream>>>(R3, w_fc2_u, fc2_b, out);
}

// Round 10
// 858.188 us; speedup vs baseline: 1.1785x; 1.0795x over previous
//
#include <hip/hip_runtime.h>
#include <hip/hip_bf16.h>

using bf16 = __hip_bfloat16;
typedef __bf16 bf16x8 __attribute__((ext_vector_type(8)));
typedef float f32x4 __attribute__((ext_vector_type(4)));

#define MROWS 100352   // 2048 windows * 49 tokens = 32*3136

__device__ __forceinline__ void async16(void* l, const void* g) {
    void* gg = const_cast<void*>(g);
    __builtin_amdgcn_global_load_lds((__attribute__((address_space(1))) void*)gg,
                                     (__attribute__((address_space(3))) void*)l, 16, 0, 0);
}

// stable tanh-approx GELU: max err vs exact erf-GELU ~7e-4, inf-safe
__device__ __forceinline__ float gelu_f(float x) {
    float u = 0.7978845608028654f * (x + 0.044715f * x * x * x);
    float e = __expf(2.0f * u);
    float t = 1.0f - 2.0f / (e + 1.0f);   // tanh(u); e=inf -> 1, e=0 -> -1
    return 0.5f * x * (1.0f + t);
}

__device__ __forceinline__ unsigned short bfu(float x) {
    bf16 b = __float2bfloat16(x);
    union { bf16 b; unsigned short u; } c; c.b = b; return c.u;
}

struct Cvt8 { const float* s[8]; bf16* d[8]; int n[8]; };

__global__ __launch_bounds__(256) void cvt8_k(Cvt8 c) {
    int seg = blockIdx.y;
    int i4 = (blockIdx.x * 256 + threadIdx.x) * 4;
    if (i4 < c.n[seg]) {
        float4 v = *(const float4*)(c.s[seg] + i4);
        bf16* d = c.d[seg] + i4;
        d[0] = __float2bfloat16(v.x);
        d[1] = __float2bfloat16(v.y);
        d[2] = __float2bfloat16(v.z);
        d[3] = __float2bfloat16(v.w);
    }
}

// Precompute attn bias (rpb + shift-mask) in C-fragment layout:
// biasf[(wt*12+h)*4096 + (ta*4+j)*256 + lane*4 + tb],
// value for n = ta*16 + (lane>>4)*4 + j, m = tb*16 + (lane&15).
// wt = (bH?2:0)|(bW?1:0). 768 KB total, L2-resident.
__global__ __launch_bounds__(256) void bias_pre_k(const float* __restrict__ rpbt,
                                                  float* __restrict__ biasf) {
    int wt = blockIdx.x / 12, h = blockIdx.x % 12;
    int t = threadIdx.x;
    int lane = t >> 2, tb = t & 3;
    int hi = lane >> 4, lo = lane & 15;
    int m = tb * 16 + lo;
    bool bH = (wt & 2) != 0, bW = (wt & 1) != 0;
    float* outb = biasf + (size_t)blockIdx.x * 4096;
    int mm = m < 49 ? m : 0;
    int i2 = mm / 7, j2 = mm % 7;
    int rm = (bH ? (i2 < 4 ? 1 : 2) : 0) * 3 + (bW ? (j2 < 4 ? 1 : 2) : 0);
#pragma unroll
    for (int ta = 0; ta < 4; ++ta) {
#pragma unroll
        for (int j = 0; j < 4; ++j) {
            int n = ta * 16 + hi * 4 + j;
            float v;
            if (n < 49 && m < 49) {
                int i1 = n / 7, j1 = n % 7;
                int rn = (bH ? (i1 < 4 ? 1 : 2) : 0) * 3 + (bW ? (j1 < 4 ? 1 : 2) : 0);
                v = rpbt[((i1 - i2 + 6) * 13 + (j1 - j2 + 6)) * 12 + h];
                if (rn != rm) v -= 100.0f;
            } else {
                v = -1e30f;
            }
            outb[(ta * 4 + j) * 256 + t] = v;
        }
    }
}

// LN1 + cyclic shift(-3,-3) + window partition. One wave per output row.
__global__ __launch_bounds__(256) void ln1_window_k(const float* __restrict__ x,
                                                    const float* __restrict__ g,
                                                    const float* __restrict__ bta,
                                                    bf16* __restrict__ ywin) {
    int wrow = blockIdx.x * 4 + (threadIdx.x >> 6);
    int lane = threadIdx.x & 63;
    int tok = wrow % 49, win = wrow / 49;
    int i = tok / 7, j = tok % 7;
    int wwi = win & 7, whi = (win >> 3) & 7, bi = win >> 6;
    int hs = (whi * 7 + i + 3) % 56;
    int ws_ = (wwi * 7 + j + 3) % 56;
    const float* xr = x + ((size_t)bi * 3136 + (size_t)hs * 56 + ws_) * 384;
    float v[6]; float s = 0.f, s2 = 0.f;
#pragma unroll
    for (int u = 0; u < 6; ++u) { float t = xr[lane + 64 * u]; v[u] = t; s += t; s2 += t * t; }
#pragma unroll
    for (int d = 1; d < 64; d <<= 1) { s += __shfl_xor(s, d); s2 += __shfl_xor(s2, d); }
    float mean = s * (1.0f / 384.0f);
    float var = s2 * (1.0f / 384.0f) - mean * mean;
    float rstd = rsqrtf(var + 1e-5f);
    bf16* yr = ywin + (size_t)wrow * 384;
#pragma unroll
    for (int u = 0; u < 6; ++u) {
        int c = lane + 64 * u;
        yr[c] = __float2bfloat16((v[u] - mean) * rstd * g[c] + bta[c]);
    }
}

// residual add (window-reverse + roll(+3,+3)) + LN2. x2 -> d_out (fp32), z -> bf16
__global__ __launch_bounds__(256) void resid_ln2_k(const float* __restrict__ x,
                                                   const bf16* __restrict__ proj,
                                                   const float* __restrict__ g,
                                                   const float* __restrict__ bta,
                                                   float* __restrict__ x2,
                                                   bf16* __restrict__ z) {
    int row = blockIdx.x * 4 + (threadIdx.x >> 6);
    int lane = threadIdx.x & 63;
    int bi = row / 3136; int hw = row % 3136;
    int h = hw / 56, w = hw % 56;
    int h2 = (h + 53) % 56, w2 = (w + 53) % 56;
    int prow = ((bi * 8 + h2 / 7) * 8 + w2 / 7) * 49 + (h2 % 7) * 7 + (w2 % 7);
    const float* xr = x + (size_t)row * 384;
    const bf16* pr = proj + (size_t)prow * 384;
    float* x2r = x2 + (size_t)row * 384;
    float v[6]; float s = 0.f, s2 = 0.f;
#pragma unroll
    for (int u = 0; u < 6; ++u) {
        int c = lane + 64 * u;
        float t = xr[c] + __bfloat162float(pr[c]);
        v[u] = t; s += t; s2 += t * t;
        x2r[c] = t;
    }
#pragma unroll
    for (int d = 1; d < 64; d <<= 1) { s += __shfl_xor(s, d); s2 += __shfl_xor(s2, d); }
    float mean = s * (1.0f / 384.0f);
    float var = s2 * (1.0f / 384.0f) - mean * mean;
    float rstd = rsqrtf(var + 1e-5f);
    bf16* zr = z + (size_t)row * 384;
#pragma unroll
    for (int u = 0; u < 6; ++u) {
        int c = lane + 64 * u;
        zr[c] = __float2bfloat16((v[u] - mean) * rstd * g[c] + bta[c]);
    }
}

// MFMA windowed attention: grid (2048 windows, 3 head-groups); 4 waves,
// one wave per head; one round per block. Barrier-free (all LDS wave-private;
// rpb+mask comes from the precomputed fragment-layout bias tile in L2).
__global__ __launch_bounds__(256) void attn_mfma_k(const bf16* __restrict__ qkv,
                                                   const float* __restrict__ biasf,
                                                   bf16* __restrict__ o) {
    __shared__ __align__(16) __bf16 vt_s[4][32 * 72];   // V^T  [d][m], m padded to 64
    __shared__ __align__(16) __bf16 p_s[4][32 * 72];    // P half [n_loc][m]
    const int win = blockIdx.x;
    const int r = blockIdx.y;
    const int wave = threadIdx.x >> 6, lane = threadIdx.x & 63;
    const int lo = lane & 15, hi = lane >> 4;
    const int whi = (win >> 3) & 7, wwi = win & 7;
    const int wt = ((whi == 7) ? 2 : 0) + ((wwi == 7) ? 1 : 0);
    __bf16* vt_w = vt_s[wave];
    __bf16* p_w = p_s[wave];
    const int h = r * 4 + wave;
    const bf16* qbase = qkv + (size_t)win * 49 * 1152 + h * 32;
    const float* btile = biasf + (size_t)(wt * 12 + h) * 4096;
    bf16x8 zf = {};

    // V -> LDS transposed; lane handles column m (write banks 2-way = free)
    {
        int m = lane;
        bf16x8 vrow[4];
#pragma unroll
        for (int d8 = 0; d8 < 4; ++d8)
            vrow[d8] = (m < 49) ? *(const bf16x8*)(qbase + (size_t)m * 1152 + 768 + d8 * 8) : zf;
#pragma unroll
        for (int d8 = 0; d8 < 4; ++d8)
#pragma unroll
            for (int e = 0; e < 8; ++e)
                vt_w[(d8 * 8 + e) * 72 + m] = vrow[d8][e];
    }
    // Q/K fragments directly from global (K-dim = 32 = one MFMA k-step)
    bf16x8 aq[4], bk[4];
    const int kq = hi * 8;
#pragma unroll
    for (int ta = 0; ta < 4; ++ta) {
        int n = ta * 16 + lo;
        aq[ta] = (n < 49) ? *(const bf16x8*)(qbase + (size_t)n * 1152 + kq) : zf;
        bk[ta] = (n < 49) ? *(const bf16x8*)(qbase + (size_t)n * 1152 + 384 + kq) : zf;
    }
    // S = Q K^T : acc[ta][tb], row n = 16ta+4hi+j, col m = 16tb+lo
    f32x4 acc[4][4] = {};
#pragma unroll
    for (int ta = 0; ta < 4; ++ta)
#pragma unroll
        for (int tb = 0; tb < 4; ++tb)
            acc[ta][tb] = __builtin_amdgcn_mfma_f32_16x16x32_bf16(aq[ta], bk[tb], acc[ta][tb], 0, 0, 0);
    // scale + precomputed (rpb+mask) bias, fragment-layout coalesced float4
#pragma unroll
    for (int ta = 0; ta < 4; ++ta) {
#pragma unroll
        for (int j = 0; j < 4; ++j) {
            float4 b4 = *(const float4*)(btile + (ta * 4 + j) * 256 + lane * 4);
            acc[ta][0][j] = fmaf(acc[ta][0][j], 0.17677669529663687f, b4.x);
            acc[ta][1][j] = fmaf(acc[ta][1][j], 0.17677669529663687f, b4.y);
            acc[ta][2][j] = fmaf(acc[ta][2][j], 0.17677669529663687f, b4.z);
            acc[ta][3][j] = fmaf(acc[ta][3][j], 0.17677669529663687f, b4.w);
        }
    }
    // V^T fragments (B-operand) hoisted once
    bf16x8 vb[2][2];
#pragma unroll
    for (int kb = 0; kb < 2; ++kb)
#pragma unroll
        for (int tb = 0; tb < 2; ++tb)
            vb[kb][tb] = *(const bf16x8*)(vt_w + (tb * 16 + lo) * 72 + kb * 32 + hi * 8);

    f32x4 oacc[4][2] = {};
    // two halves of 32 rows: softmax -> P half tile -> PV
#pragma unroll
    for (int half = 0; half < 2; ++half) {
#pragma unroll
        for (int tq = 0; tq < 2; ++tq) {
            int ta = half * 2 + tq;
#pragma unroll
            for (int j = 0; j < 4; ++j) {
                float mx = fmaxf(fmaxf(acc[ta][0][j], acc[ta][1][j]),
                                 fmaxf(acc[ta][2][j], acc[ta][3][j]));
                mx = fmaxf(mx, __shfl_xor(mx, 1));
                mx = fmaxf(mx, __shfl_xor(mx, 2));
                mx = fmaxf(mx, __shfl_xor(mx, 4));
                mx = fmaxf(mx, __shfl_xor(mx, 8));
                float e0 = __expf(acc[ta][0][j] - mx);
                float e1 = __expf(acc[ta][1][j] - mx);
                float e2 = __expf(acc[ta][2][j] - mx);
                float e3 = __expf(acc[ta][3][j] - mx);
                float sm = e0 + e1 + e2 + e3;
                sm += __shfl_xor(sm, 1);
                sm += __shfl_xor(sm, 2);
                sm += __shfl_xor(sm, 4);
                sm += __shfl_xor(sm, 8);
                float inv = 1.0f / sm;
                int nl = tq * 16 + hi * 4 + j;
                p_w[nl * 72 + lo]      = (__bf16)(e0 * inv);
                p_w[nl * 72 + 16 + lo] = (__bf16)(e1 * inv);
                p_w[nl * 72 + 32 + lo] = (__bf16)(e2 * inv);
                p_w[nl * 72 + 48 + lo] = (__bf16)(e3 * inv);
            }
        }
#pragma unroll
        for (int kb = 0; kb < 2; ++kb) {
#pragma unroll
            for (int tq = 0; tq < 2; ++tq) {
                bf16x8 pa = *(const bf16x8*)(p_w + (tq * 16 + lo) * 72 + kb * 32 + hi * 8);
#pragma unroll
                for (int tb = 0; tb < 2; ++tb)
                    oacc[half * 2 + tq][tb] =
                        __builtin_amdgcn_mfma_f32_16x16x32_bf16(pa, vb[kb][tb], oacc[half * 2 + tq][tb], 0, 0, 0);
            }
        }
    }
    bf16* obase = o + (size_t)win * 49 * 384 + h * 32;
#pragma unroll
    for (int ta = 0; ta < 4; ++ta) {
#pragma unroll
        for (int j = 0; j < 4; ++j) {
            int n = ta * 16 + hi * 4 + j;
            if (n < 49) {
#pragma unroll
                for (int tb = 0; tb < 2; ++tb)
                    obase[(size_t)n * 384 + tb * 16 + lo] = __float2bfloat16(oacc[ta][tb][j]);
            }
        }
    }
}

// C[M,N] = A[M,K] bf16 @ W[N,K]^T bf16.  BK=64, 24 KB LDS -> 6 blocks/CU.
// __launch_bounds__(256,6): VGPR budget 512/6=85 (was 44 -- allocator had
// ZERO regs for addressing and recomputed every address; that was the VALU
// bottleneck). Staging bases hoisted: gslot = (t&7)^((t>>3)&7) is i/kt-
// independent. Swapped operands; packed uint2 stores; XCD-chunked swizzle.
template <int K, int EPI>
__global__ __launch_bounds__(256, 6) void gemm_bt(const bf16* __restrict__ A,
                                                  const bf16* __restrict__ W,
                                                  const float* __restrict__ bias,
                                                  void* __restrict__ Cout,
                                                  int N) {
    __shared__ __align__(16) bf16 lds_a[128 * 64];
    __shared__ __align__(16) bf16 lds_b[64 * 64];
    const int t = threadIdx.x;
    const int wave = t >> 6, lane = t & 63;
    const int gdx = gridDim.x;
    int flat = blockIdx.y * gdx + blockIdx.x;
    int q = (gdx * gridDim.y) >> 3;
    int work = (flat & 7) * q + (flat >> 3);
    const int n0 = (work % gdx) * 64, m0 = (work / gdx) * 128;
    const int wm = wave >> 1, wn = wave & 1;
    const int fr = lane & 15, hi = lane >> 4;
    // hoisted staging addresses (row = 32*i + (t>>3), slot = t&7)
    const int srow = t >> 3;
    const int gslot = (t & 7) ^ (srow & 7);
    const bf16* abase = A + (size_t)(m0 + srow) * K + gslot * 8;
    const bf16* bbase = W + (size_t)(n0 + srow) * K + gslot * 8;
    char* la = (char*)lds_a + t * 16;
    char* lb = (char*)lds_b + t * 16;
    f32x4 acc[4][2] = {};
    for (int kt = 0; kt < K; kt += 64) {
        if (kt > 0) __syncthreads();
#pragma unroll
        for (int i = 0; i < 4; ++i)
            async16(la + i * 4096, abase + (size_t)i * 32 * K + kt);
#pragma unroll
        for (int i = 0; i < 2; ++i)
            async16(lb + i * 4096, bbase + (size_t)i * 32 * K + kt);
        __syncthreads();
#pragma unroll
        for (int ks = 0; ks < 2; ++ks) {
            bf16x8 af[4], bfr[2];
#pragma unroll
            for (int mi = 0; mi < 4; ++mi) {
                int row = wm * 64 + mi * 16 + fr;
                int slot = (ks * 4 + hi) ^ (row & 7);
                af[mi] = *(const bf16x8*)((const char*)lds_a + row * 128 + slot * 16);
            }
#pragma unroll
            for (int ni = 0; ni < 2; ++ni) {
                int row = wn * 32 + ni * 16 + fr;
                int slot = (ks * 4 + hi) ^ (row & 7);
                bfr[ni] = *(const bf16x8*)((const char*)lds_b + row * 128 + slot * 16);
            }
#pragma unroll
            for (int mi = 0; mi < 4; ++mi)
#pragma unroll
                for (int ni = 0; ni < 2; ++ni)
                    acc[mi][ni] = __builtin_amdgcn_mfma_f32_16x16x32_bf16(bfr[ni], af[mi], acc[mi][ni], 0, 0, 0);
        }
    }
    const int rq4 = hi * 4;
#pragma unroll
    for (int mi = 0; mi < 4; ++mi) {
        int m = m0 + wm * 64 + mi * 16 + fr;
        size_t rowb = (size_t)m * N;
#pragma unroll
        for (int ni = 0; ni < 2; ++ni) {
            int nb = n0 + wn * 32 + ni * 16 + rq4;
            float v0 = acc[mi][ni][0], v1 = acc[mi][ni][1];
            float v2 = acc[mi][ni][2], v3 = acc[mi][ni][3];
            if (bias) {
                float4 b4 = *(const float4*)(bias + nb);
                v0 += b4.x; v1 += b4.y; v2 += b4.z; v3 += b4.w;
            }
            if (EPI == 1) { v0 = gelu_f(v0); v1 = gelu_f(v1); v2 = gelu_f(v2); v3 = gelu_f(v3); }
            if (EPI == 2) {
                float4* p = (float4*)((float*)Cout + rowb + nb);
                float4 o = *p;
                o.x += v0; o.y += v1; o.z += v2; o.w += v3;
                *p = o;
            } else {
                uint2 st;
                st.x = (unsigned)bfu(v0) | ((unsigned)bfu(v1) << 16);
                st.y = (unsigned)bfu(v2) | ((unsigned)bfu(v3) << 16);
                *(uint2*)((bf16*)Cout + rowb + nb) = st;
            }
        }
    }
}

extern "C" void kernel_launch(void* const* d_in, const int* in_sizes, int n_in,
                              void* d_out, int out_size, void* d_ws, size_t ws_size,
                              hipStream_t stream) {
    const float* x      = (const float*)d_in[0];
    const float* n1g    = (const float*)d_in[1];
    const float* n1b    = (const float*)d_in[2];
    const float* rpbt   = (const float*)d_in[3];
    const float* qkv_v  = (const float*)d_in[4];
    const float* qkv_u  = (const float*)d_in[5];
    const float* qkv_b  = (const float*)d_in[6];
    const float* proj_v = (const float*)d_in[7];
    const float* proj_u = (const float*)d_in[8];
    const float* proj_b = (const float*)d_in[9];
    const float* n2g    = (const float*)d_in[10];
    const float* n2b    = (const float*)d_in[11];
    const float* fc1_v  = (const float*)d_in[12];
    const float* fc1_u  = (const float*)d_in[13];
    const float* fc1_b  = (const float*)d_in[14];
    const float* fc2_v  = (const float*)d_in[15];
    const float* fc2_u  = (const float*)d_in[16];
    const float* fc2_b  = (const float*)d_in[17];

    char* ws = (char*)d_ws;
    bf16* wb = (bf16*)ws;
    bf16* w_qkv_v  = wb;
    bf16* w_qkv_u  = wb + 73728;
    bf16* w_proj_v = wb + 294912;
    bf16* w_proj_u = wb + 368640;
    bf16* w_fc1_v  = wb + 442368;
    bf16* w_fc1_u  = wb + 516096;
    bf16* w_fc2_v  = wb + 811008;
    bf16* w_fc2_u  = wb + 1105920;
    float* biasf   = (float*)(ws + 3145728);   // 768 KB, ends < 4 MB
    size_t off = (size_t)4 << 20;
    bf16* R1 = (bf16*)(ws + off); off += (size_t)MROWS * 1536 * 2;   // qkv / proj / mlp-hidden
    bf16* R2 = (bf16*)(ws + off); off += (size_t)MROWS * 384 * 2;    // ywin / o / z
    bf16* R3 = (bf16*)(ws + off);                                    // t1/t2/t3/t4 (M x 192)
    float* out = (float*)d_out;

    Cvt8 c;
    c.s[0] = qkv_v;  c.d[0] = w_qkv_v;  c.n[0] = 73728;
    c.s[1] = qkv_u;  c.d[1] = w_qkv_u;  c.n[1] = 221184;
    c.s[2] = proj_v; c.d[2] = w_proj_v; c.n[2] = 73728;
    c.s[3] = proj_u; c.d[3] = w_proj_u; c.n[3] = 73728;
    c.s[4] = fc1_v;  c.d[4] = w_fc1_v;  c.n[4] = 73728;
    c.s[5] = fc1_u;  c.d[5] = w_fc1_u;  c.n[5] = 294912;
    c.s[6] = fc2_v;  c.d[6] = w_fc2_v;  c.n[6] = 294912;
    c.s[7] = fc2_u;  c.d[7] = w_fc2_u;  c.n[7] = 73728;
    cvt8_k<<<dim3(288, 8), 256, 0, stream>>>(c);
    bias_pre_k<<<48, 256, 0, stream>>>(rpbt, biasf);

    ln1_window_k<<<MROWS / 4, 256, 0, stream>>>(x, n1g, n1b, R2);
    gemm_bt<384, 0><<<dim3(3, 784), 256, 0, stream>>>(R2, w_qkv_v, nullptr, R3, 192);
    gemm_bt<192, 0><<<dim3(18, 784), 256, 0, stream>>>(R3, w_qkv_u, qkv_b, R1, 1152);
    attn_mfma_k<<<dim3(2048, 3), 256, 0, stream>>>(R1, biasf, R2);
    gemm_bt<384, 0><<<dim3(3, 784), 256, 0, stream>>>(R2, w_proj_v, nullptr, R3, 192);
    gemm_bt<192, 0><<<dim3(6, 784), 256, 0, stream>>>(R3, w_proj_u, proj_b, R1, 384);
    resid_ln2_k<<<MROWS / 4, 256, 0, stream>>>(x, R1, n2g, n2b, out, R2);
    gemm_bt<384, 0><<<dim3(3, 784), 256, 0, stream>>>(R2, w_fc1_v, nullptr, R3, 192);
    gemm_bt<192, 1><<<dim3(24, 784), 256, 0, stream>>>(R3, w_fc1_u, fc1_b, R1, 1536);
    gemm_bt<1536, 0><<<dim3(3, 784), 256, 0, stream>>>(R1, w_fc2_v, nullptr, R3, 192);
    gemm_bt<192, 2><<<dim3(6, 784), 256, 0, stream>>>(R3, w_fc2_u, fc2_b, out, 384);
}

// Round 11
// 847.890 us; speedup vs baseline: 1.1928x; 1.0121x over previous
//
#include <hip/hip_runtime.h>
#include <hip/hip_bf16.h>

using bf16 = __hip_bfloat16;
typedef __bf16 bf16x8 __attribute__((ext_vector_type(8)));
typedef __bf16 bf16x4v __attribute__((ext_vector_type(4)));
typedef float f32x4 __attribute__((ext_vector_type(4)));

#define MROWS 100352   // 2048 windows * 49 tokens = 32*3136

__device__ __forceinline__ void async16(void* l, const void* g) {
    void* gg = const_cast<void*>(g);
    __builtin_amdgcn_global_load_lds((__attribute__((address_space(1))) void*)gg,
                                     (__attribute__((address_space(3))) void*)l, 16, 0, 0);
}

// stable tanh-approx GELU: max err vs exact erf-GELU ~7e-4, inf-safe
__device__ __forceinline__ float gelu_f(float x) {
    float u = 0.7978845608028654f * (x + 0.044715f * x * x * x);
    float e = __expf(2.0f * u);
    float t = 1.0f - 2.0f / (e + 1.0f);   // tanh(u); e=inf -> 1, e=0 -> -1
    return 0.5f * x * (1.0f + t);
}

struct Cvt8 { const float* s[8]; bf16* d[8]; int n[8]; };

__global__ __launch_bounds__(256) void cvt8_k(Cvt8 c) {
    int seg = blockIdx.y;
    int i4 = (blockIdx.x * 256 + threadIdx.x) * 4;
    if (i4 < c.n[seg]) {
        float4 v = *(const float4*)(c.s[seg] + i4);
        bf16* d = c.d[seg] + i4;
        d[0] = __float2bfloat16(v.x);
        d[1] = __float2bfloat16(v.y);
        d[2] = __float2bfloat16(v.z);
        d[3] = __float2bfloat16(v.w);
    }
}

// Precompute attn bias (rpb + shift-mask) in C-fragment layout:
// biasf[(wt*12+h)*4096 + (ta*4+j)*256 + lane*4 + tb]
__global__ __launch_bounds__(256) void bias_pre_k(const float* __restrict__ rpbt,
                                                  float* __restrict__ biasf) {
    int wt = blockIdx.x / 12, h = blockIdx.x % 12;
    int t = threadIdx.x;
    int lane = t >> 2, tb = t & 3;
    int hi = lane >> 4, lo = lane & 15;
    int m = tb * 16 + lo;
    bool bH = (wt & 2) != 0, bW = (wt & 1) != 0;
    float* outb = biasf + (size_t)blockIdx.x * 4096;
    int mm = m < 49 ? m : 0;
    int i2 = mm / 7, j2 = mm % 7;
    int rm = (bH ? (i2 < 4 ? 1 : 2) : 0) * 3 + (bW ? (j2 < 4 ? 1 : 2) : 0);
#pragma unroll
    for (int ta = 0; ta < 4; ++ta) {
#pragma unroll
        for (int j = 0; j < 4; ++j) {
            int n = ta * 16 + hi * 4 + j;
            float v;
            if (n < 49 && m < 49) {
                int i1 = n / 7, j1 = n % 7;
                int rn = (bH ? (i1 < 4 ? 1 : 2) : 0) * 3 + (bW ? (j1 < 4 ? 1 : 2) : 0);
                v = rpbt[((i1 - i2 + 6) * 13 + (j1 - j2 + 6)) * 12 + h];
                if (rn != rm) v -= 100.0f;
            } else {
                v = -1e30f;
            }
            outb[(ta * 4 + j) * 256 + t] = v;
        }
    }
}

// LN1 + cyclic shift(-3,-3) + window partition. One wave per output row.
__global__ __launch_bounds__(256) void ln1_window_k(const float* __restrict__ x,
                                                    const float* __restrict__ g,
                                                    const float* __restrict__ bta,
                                                    bf16* __restrict__ ywin) {
    int wrow = blockIdx.x * 4 + (threadIdx.x >> 6);
    int lane = threadIdx.x & 63;
    int tok = wrow % 49, win = wrow / 49;
    int i = tok / 7, j = tok % 7;
    int wwi = win & 7, whi = (win >> 3) & 7, bi = win >> 6;
    int hs = (whi * 7 + i + 3) % 56;
    int ws_ = (wwi * 7 + j + 3) % 56;
    const float* xr = x + ((size_t)bi * 3136 + (size_t)hs * 56 + ws_) * 384;
    float v[6]; float s = 0.f, s2 = 0.f;
#pragma unroll
    for (int u = 0; u < 6; ++u) { float t = xr[lane + 64 * u]; v[u] = t; s += t; s2 += t * t; }
#pragma unroll
    for (int d = 1; d < 64; d <<= 1) { s += __shfl_xor(s, d); s2 += __shfl_xor(s2, d); }
    float mean = s * (1.0f / 384.0f);
    float var = s2 * (1.0f / 384.0f) - mean * mean;
    float rstd = rsqrtf(var + 1e-5f);
    bf16* yr = ywin + (size_t)wrow * 384;
#pragma unroll
    for (int u = 0; u < 6; ++u) {
        int c = lane + 64 * u;
        yr[c] = __float2bfloat16((v[u] - mean) * rstd * g[c] + bta[c]);
    }
}

// residual add (window-reverse + roll(+3,+3)) + LN2. x2 -> d_out (fp32), z -> bf16
__global__ __launch_bounds__(256) void resid_ln2_k(const float* __restrict__ x,
                                                   const bf16* __restrict__ proj,
                                                   const float* __restrict__ g,
                                                   const float* __restrict__ bta,
                                                   float* __restrict__ x2,
                                                   bf16* __restrict__ z) {
    int row = blockIdx.x * 4 + (threadIdx.x >> 6);
    int lane = threadIdx.x & 63;
    int bi = row / 3136; int hw = row % 3136;
    int h = hw / 56, w = hw % 56;
    int h2 = (h + 53) % 56, w2 = (w + 53) % 56;
    int prow = ((bi * 8 + h2 / 7) * 8 + w2 / 7) * 49 + (h2 % 7) * 7 + (w2 % 7);
    const float* xr = x + (size_t)row * 384;
    const bf16* pr = proj + (size_t)prow * 384;
    float* x2r = x2 + (size_t)row * 384;
    float v[6]; float s = 0.f, s2 = 0.f;
#pragma unroll
    for (int u = 0; u < 6; ++u) {
        int c = lane + 64 * u;
        float t = xr[c] + __bfloat162float(pr[c]);
        v[u] = t; s += t; s2 += t * t;
        x2r[c] = t;
    }
#pragma unroll
    for (int d = 1; d < 64; d <<= 1) { s += __shfl_xor(s, d); s2 += __shfl_xor(s2, d); }
    float mean = s * (1.0f / 384.0f);
    float var = s2 * (1.0f / 384.0f) - mean * mean;
    float rstd = rsqrtf(var + 1e-5f);
    bf16* zr = z + (size_t)row * 384;
#pragma unroll
    for (int u = 0; u < 6; ++u) {
        int c = lane + 64 * u;
        zr[c] = __float2bfloat16((v[u] - mean) * rstd * g[c] + bta[c]);
    }
}

// MFMA windowed attention: grid (2048 windows, 3 head-groups); 4 waves,
// one wave per head; barrier-free; precomputed fragment-layout bias.
__global__ __launch_bounds__(256) void attn_mfma_k(const bf16* __restrict__ qkv,
                                                   const float* __restrict__ biasf,
                                                   bf16* __restrict__ o) {
    __shared__ __align__(16) __bf16 vt_s[4][32 * 72];   // V^T  [d][m], m padded to 64
    __shared__ __align__(16) __bf16 p_s[4][32 * 72];    // P half [n_loc][m]
    const int win = blockIdx.x;
    const int r = blockIdx.y;
    const int wave = threadIdx.x >> 6, lane = threadIdx.x & 63;
    const int lo = lane & 15, hi = lane >> 4;
    const int whi = (win >> 3) & 7, wwi = win & 7;
    const int wt = ((whi == 7) ? 2 : 0) + ((wwi == 7) ? 1 : 0);
    __bf16* vt_w = vt_s[wave];
    __bf16* p_w = p_s[wave];
    const int h = r * 4 + wave;
    const bf16* qbase = qkv + (size_t)win * 49 * 1152 + h * 32;
    const float* btile = biasf + (size_t)(wt * 12 + h) * 4096;
    bf16x8 zf = {};

    // V -> LDS transposed; lane handles column m
    {
        int m = lane;
        bf16x8 vrow[4];
#pragma unroll
        for (int d8 = 0; d8 < 4; ++d8)
            vrow[d8] = (m < 49) ? *(const bf16x8*)(qbase + (size_t)m * 1152 + 768 + d8 * 8) : zf;
#pragma unroll
        for (int d8 = 0; d8 < 4; ++d8)
#pragma unroll
            for (int e = 0; e < 8; ++e)
                vt_w[(d8 * 8 + e) * 72 + m] = vrow[d8][e];
    }
    bf16x8 aq[4], bk[4];
    const int kq = hi * 8;
#pragma unroll
    for (int ta = 0; ta < 4; ++ta) {
        int n = ta * 16 + lo;
        aq[ta] = (n < 49) ? *(const bf16x8*)(qbase + (size_t)n * 1152 + kq) : zf;
        bk[ta] = (n < 49) ? *(const bf16x8*)(qbase + (size_t)n * 1152 + 384 + kq) : zf;
    }
    f32x4 acc[4][4] = {};
#pragma unroll
    for (int ta = 0; ta < 4; ++ta)
#pragma unroll
        for (int tb = 0; tb < 4; ++tb)
            acc[ta][tb] = __builtin_amdgcn_mfma_f32_16x16x32_bf16(aq[ta], bk[tb], acc[ta][tb], 0, 0, 0);
#pragma unroll
    for (int ta = 0; ta < 4; ++ta) {
#pragma unroll
        for (int j = 0; j < 4; ++j) {
            float4 b4 = *(const float4*)(btile + (ta * 4 + j) * 256 + lane * 4);
            acc[ta][0][j] = fmaf(acc[ta][0][j], 0.17677669529663687f, b4.x);
            acc[ta][1][j] = fmaf(acc[ta][1][j], 0.17677669529663687f, b4.y);
            acc[ta][2][j] = fmaf(acc[ta][2][j], 0.17677669529663687f, b4.z);
            acc[ta][3][j] = fmaf(acc[ta][3][j], 0.17677669529663687f, b4.w);
        }
    }
    bf16x8 vb[2][2];
#pragma unroll
    for (int kb = 0; kb < 2; ++kb)
#pragma unroll
        for (int tb = 0; tb < 2; ++tb)
            vb[kb][tb] = *(const bf16x8*)(vt_w + (tb * 16 + lo) * 72 + kb * 32 + hi * 8);

    f32x4 oacc[4][2] = {};
#pragma unroll
    for (int half = 0; half < 2; ++half) {
#pragma unroll
        for (int tq = 0; tq < 2; ++tq) {
            int ta = half * 2 + tq;
#pragma unroll
            for (int j = 0; j < 4; ++j) {
                float mx = fmaxf(fmaxf(acc[ta][0][j], acc[ta][1][j]),
                                 fmaxf(acc[ta][2][j], acc[ta][3][j]));
                mx = fmaxf(mx, __shfl_xor(mx, 1));
                mx = fmaxf(mx, __shfl_xor(mx, 2));
                mx = fmaxf(mx, __shfl_xor(mx, 4));
                mx = fmaxf(mx, __shfl_xor(mx, 8));
                float e0 = __expf(acc[ta][0][j] - mx);
                float e1 = __expf(acc[ta][1][j] - mx);
                float e2 = __expf(acc[ta][2][j] - mx);
                float e3 = __expf(acc[ta][3][j] - mx);
                float sm = e0 + e1 + e2 + e3;
                sm += __shfl_xor(sm, 1);
                sm += __shfl_xor(sm, 2);
                sm += __shfl_xor(sm, 4);
                sm += __shfl_xor(sm, 8);
                float inv = 1.0f / sm;
                int nl = tq * 16 + hi * 4 + j;
                p_w[nl * 72 + lo]      = (__bf16)(e0 * inv);
                p_w[nl * 72 + 16 + lo] = (__bf16)(e1 * inv);
                p_w[nl * 72 + 32 + lo] = (__bf16)(e2 * inv);
                p_w[nl * 72 + 48 + lo] = (__bf16)(e3 * inv);
            }
        }
#pragma unroll
        for (int kb = 0; kb < 2; ++kb) {
#pragma unroll
            for (int tq = 0; tq < 2; ++tq) {
                bf16x8 pa = *(const bf16x8*)(p_w + (tq * 16 + lo) * 72 + kb * 32 + hi * 8);
#pragma unroll
                for (int tb = 0; tb < 2; ++tb)
                    oacc[half * 2 + tq][tb] =
                        __builtin_amdgcn_mfma_f32_16x16x32_bf16(pa, vb[kb][tb], oacc[half * 2 + tq][tb], 0, 0, 0);
            }
        }
    }
    bf16* obase = o + (size_t)win * 49 * 384 + h * 32;
#pragma unroll
    for (int ta = 0; ta < 4; ++ta) {
#pragma unroll
        for (int j = 0; j < 4; ++j) {
            int n = ta * 16 + hi * 4 + j;
            if (n < 49) {
#pragma unroll
                for (int tb = 0; tb < 2; ++tb)
                    obase[(size_t)n * 384 + tb * 16 + lo] = __float2bfloat16(oacc[ta][tb][j]);
            }
        }
    }
}

// C[M,N] = A[M,K] bf16 @ W[N,K]^T bf16. Template over WN (n-waves):
// WN=2: 256 thr, 128x64 tile, 24 KB (N=192 GEMMs); WN=4: 512 thr, 128x128
// tile, 32 KB -> 4 blocks x 8 waves = 32 waves/CU (100% occupancy cap).
// BK=64; slot-XOR both-sides (0 conflicts measured); swapped operands;
// (__bf16)-cast bf16x4 stores (v_cvt_pk path); XCD-chunked swizzle.
template <int K, int WN, int EPI>
__global__ __launch_bounds__(WN * 128, 8 - WN) void gemm_bt(const bf16* __restrict__ A,
                                                            const bf16* __restrict__ W,
                                                            const float* __restrict__ bias,
                                                            void* __restrict__ Cout,
                                                            int N) {
    constexpr int T = WN * 128;
    constexpr int BN = WN * 32;
    __shared__ __align__(16) bf16 lds_a[128 * 64];
    __shared__ __align__(16) bf16 lds_b[BN * 64];
    const int t = threadIdx.x;
    const int wave = t >> 6, lane = t & 63;
    const int gdx = gridDim.x;
    int flat = blockIdx.y * gdx + blockIdx.x;
    int q = (gdx * gridDim.y) >> 3;
    int work = (flat & 7) * q + (flat >> 3);
    const int n0 = (work % gdx) * BN, m0 = (work / gdx) * 128;
    const int wm = wave / WN, wn = wave % WN;
    const int fr = lane & 15, hi = lane >> 4;
    // hoisted staging addresses (unit u = i*T + t; row = u>>3, slot = u&7)
    const int srow = t >> 3;
    const int gslot = (t & 7) ^ (srow & 7);
    const bf16* abase = A + (size_t)(m0 + srow) * K + gslot * 8;
    const bf16* bbase = W + (size_t)(n0 + srow) * K + gslot * 8;
    char* la = (char*)lds_a + t * 16;
    char* lb = (char*)lds_b + t * 16;
    f32x4 acc[4][2] = {};
    for (int kt = 0; kt < K; kt += 64) {
        if (kt > 0) __syncthreads();
#pragma unroll
        for (int i = 0; i < 1024 / T; ++i)
            async16(la + i * T * 16, abase + (size_t)i * (T >> 3) * K + kt);
#pragma unroll
        for (int i = 0; i < BN * 8 / T; ++i)
            async16(lb + i * T * 16, bbase + (size_t)i * (T >> 3) * K + kt);
        __syncthreads();
#pragma unroll
        for (int ks = 0; ks < 2; ++ks) {
            bf16x8 af[4], bfr[2];
#pragma unroll
            for (int mi = 0; mi < 4; ++mi) {
                int row = wm * 64 + mi * 16 + fr;
                int slot = (ks * 4 + hi) ^ (row & 7);
                af[mi] = *(const bf16x8*)((const char*)lds_a + row * 128 + slot * 16);
            }
#pragma unroll
            for (int ni = 0; ni < 2; ++ni) {
                int row = wn * 32 + ni * 16 + fr;
                int slot = (ks * 4 + hi) ^ (row & 7);
                bfr[ni] = *(const bf16x8*)((const char*)lds_b + row * 128 + slot * 16);
            }
#pragma unroll
            for (int mi = 0; mi < 4; ++mi)
#pragma unroll
                for (int ni = 0; ni < 2; ++ni)
                    acc[mi][ni] = __builtin_amdgcn_mfma_f32_16x16x32_bf16(bfr[ni], af[mi], acc[mi][ni], 0, 0, 0);
        }
    }
    const int rq4 = hi * 4;
#pragma unroll
    for (int mi = 0; mi < 4; ++mi) {
        int m = m0 + wm * 64 + mi * 16 + fr;
        size_t rowb = (size_t)m * N;
#pragma unroll
        for (int ni = 0; ni < 2; ++ni) {
            int nb = n0 + wn * 32 + ni * 16 + rq4;
            float v0 = acc[mi][ni][0], v1 = acc[mi][ni][1];
            float v2 = acc[mi][ni][2], v3 = acc[mi][ni][3];
            if (bias) {
                float4 b4 = *(const float4*)(bias + nb);
                v0 += b4.x; v1 += b4.y; v2 += b4.z; v3 += b4.w;
            }
            if (EPI == 1) { v0 = gelu_f(v0); v1 = gelu_f(v1); v2 = gelu_f(v2); v3 = gelu_f(v3); }
            if (EPI == 2) {
                float4* p = (float4*)((float*)Cout + rowb + nb);
                float4 o = *p;
                o.x += v0; o.y += v1; o.z += v2; o.w += v3;
                *p = o;
            } else {
                bf16x4v st = { (__bf16)v0, (__bf16)v1, (__bf16)v2, (__bf16)v3 };
                *(bf16x4v*)((bf16*)Cout + rowb + nb) = st;
            }
        }
    }
}

extern "C" void kernel_launch(void* const* d_in, const int* in_sizes, int n_in,
                              void* d_out, int out_size, void* d_ws, size_t ws_size,
                              hipStream_t stream) {
    const float* x      = (const float*)d_in[0];
    const float* n1g    = (const float*)d_in[1];
    const float* n1b    = (const float*)d_in[2];
    const float* rpbt   = (const float*)d_in[3];
    const float* qkv_v  = (const float*)d_in[4];
    const float* qkv_u  = (const float*)d_in[5];
    const float* qkv_b  = (const float*)d_in[6];
    const float* proj_v = (const float*)d_in[7];
    const float* proj_u = (const float*)d_in[8];
    const float* proj_b = (const float*)d_in[9];
    const float* n2g    = (const float*)d_in[10];
    const float* n2b    = (const float*)d_in[11];
    const float* fc1_v  = (const float*)d_in[12];
    const float* fc1_u  = (const float*)d_in[13];
    const float* fc1_b  = (const float*)d_in[14];
    const float* fc2_v  = (const float*)d_in[15];
    const float* fc2_u  = (const float*)d_in[16];
    const float* fc2_b  = (const float*)d_in[17];

    char* ws = (char*)d_ws;
    bf16* wb = (bf16*)ws;
    bf16* w_qkv_v  = wb;
    bf16* w_qkv_u  = wb + 73728;
    bf16* w_proj_v = wb + 294912;
    bf16* w_proj_u = wb + 368640;
    bf16* w_fc1_v  = wb + 442368;
    bf16* w_fc1_u  = wb + 516096;
    bf16* w_fc2_v  = wb + 811008;
    bf16* w_fc2_u  = wb + 1105920;
    float* biasf   = (float*)(ws + 3145728);   // 768 KB, ends < 4 MB
    size_t off = (size_t)4 << 20;
    bf16* R1 = (bf16*)(ws + off); off += (size_t)MROWS * 1536 * 2;   // qkv / proj / mlp-hidden
    bf16* R2 = (bf16*)(ws + off); off += (size_t)MROWS * 384 * 2;    // ywin / o / z
    bf16* R3 = (bf16*)(ws + off);                                    // t1/t2/t3/t4 (M x 192)
    float* out = (float*)d_out;

    Cvt8 c;
    c.s[0] = qkv_v;  c.d[0] = w_qkv_v;  c.n[0] = 73728;
    c.s[1] = qkv_u;  c.d[1] = w_qkv_u;  c.n[1] = 221184;
    c.s[2] = proj_v; c.d[2] = w_proj_v; c.n[2] = 73728;
    c.s[3] = proj_u; c.d[3] = w_proj_u; c.n[3] = 73728;
    c.s[4] = fc1_v;  c.d[4] = w_fc1_v;  c.n[4] = 73728;
    c.s[5] = fc1_u;  c.d[5] = w_fc1_u;  c.n[5] = 294912;
    c.s[6] = fc2_v;  c.d[6] = w_fc2_v;  c.n[6] = 294912;
    c.s[7] = fc2_u;  c.d[7] = w_fc2_u;  c.n[7] = 73728;
    cvt8_k<<<dim3(288, 8), 256, 0, stream>>>(c);
    bias_pre_k<<<48, 256, 0, stream>>>(rpbt, biasf);

    ln1_window_k<<<MROWS / 4, 256, 0, stream>>>(x, n1g, n1b, R2);
    gemm_bt<384, 2, 0><<<dim3(3, 784), 256, 0, stream>>>(R2, w_qkv_v, nullptr, R3, 192);
    gemm_bt<192, 4, 0><<<dim3(9, 784), 512, 0, stream>>>(R3, w_qkv_u, qkv_b, R1, 1152);
    attn_mfma_k<<<dim3(2048, 3), 256, 0, stream>>>(R1, biasf, R2);
    gemm_bt<384, 2, 0><<<dim3(3, 784), 256, 0, stream>>>(R2, w_proj_v, nullptr, R3, 192);
    gemm_bt<192, 4, 0><<<dim3(3, 784), 512, 0, stream>>>(R3, w_proj_u, proj_b, R1, 384);
    resid_ln2_k<<<MROWS / 4, 256, 0, stream>>>(x, R1, n2g, n2b, out, R2);
    gemm_bt<384, 2, 0><<<dim3(3, 784), 256, 0, stream>>>(R2, w_fc1_v, nullptr, R3, 192);
    gemm_bt<192, 4, 1><<<dim3(12, 784), 512, 0, stream>>>(R3, w_fc1_u, fc1_b, R1, 1536);
    gemm_bt<1536, 2, 0><<<dim3(3, 784), 256, 0, stream>>>(R1, w_fc2_v, nullptr, R3, 192);
    gemm_bt<192, 4, 2><<<dim3(3, 784), 512, 0, stream>>>(R3, w_fc2_u, fc2_b, out, 384);
}

// Round 12
// 841.832 us; speedup vs baseline: 1.2014x; 1.0072x over previous
//
#include <hip/hip_runtime.h>
#include <hip/hip_bf16.h>

using bf16 = __hip_bfloat16;
typedef __bf16 bf16x8 __attribute__((ext_vector_type(8)));
typedef __bf16 bf16x4v __attribute__((ext_vector_type(4)));
typedef float f32x4 __attribute__((ext_vector_type(4)));

#define MROWS 100352   // 2048 windows * 49 tokens = 32*3136

__device__ __forceinline__ void async16(void* l, const void* g) {
    void* gg = const_cast<void*>(g);
    __builtin_amdgcn_global_load_lds((__attribute__((address_space(1))) void*)gg,
                                     (__attribute__((address_space(3))) void*)l, 16, 0, 0);
}

// stable tanh-approx GELU: max err vs exact erf-GELU ~7e-4, inf-safe
__device__ __forceinline__ float gelu_f(float x) {
    float u = 0.7978845608028654f * (x + 0.044715f * x * x * x);
    float e = __expf(2.0f * u);
    float t = 1.0f - 2.0f / (e + 1.0f);   // tanh(u); e=inf -> 1, e=0 -> -1
    return 0.5f * x * (1.0f + t);
}

struct Cvt8 { const float* s[8]; bf16* d[8]; int n[8]; };

__global__ __launch_bounds__(256) void cvt8_k(Cvt8 c) {
    int seg = blockIdx.y;
    int i4 = (blockIdx.x * 256 + threadIdx.x) * 4;
    if (i4 < c.n[seg]) {
        float4 v = *(const float4*)(c.s[seg] + i4);
        bf16* d = c.d[seg] + i4;
        d[0] = __float2bfloat16(v.x);
        d[1] = __float2bfloat16(v.y);
        d[2] = __float2bfloat16(v.z);
        d[3] = __float2bfloat16(v.w);
    }
}

// Precompute attn bias (rpb + shift-mask) in C-fragment layout:
// biasf[(wt*12+h)*4096 + (ta*4+j)*256 + lane*4 + tb]
__global__ __launch_bounds__(256) void bias_pre_k(const float* __restrict__ rpbt,
                                                  float* __restrict__ biasf) {
    int wt = blockIdx.x / 12, h = blockIdx.x % 12;
    int t = threadIdx.x;
    int lane = t >> 2, tb = t & 3;
    int hi = lane >> 4, lo = lane & 15;
    int m = tb * 16 + lo;
    bool bH = (wt & 2) != 0, bW = (wt & 1) != 0;
    float* outb = biasf + (size_t)blockIdx.x * 4096;
    int mm = m < 49 ? m : 0;
    int i2 = mm / 7, j2 = mm % 7;
    int rm = (bH ? (i2 < 4 ? 1 : 2) : 0) * 3 + (bW ? (j2 < 4 ? 1 : 2) : 0);
#pragma unroll
    for (int ta = 0; ta < 4; ++ta) {
#pragma unroll
        for (int j = 0; j < 4; ++j) {
            int n = ta * 16 + hi * 4 + j;
            float v;
            if (n < 49 && m < 49) {
                int i1 = n / 7, j1 = n % 7;
                int rn = (bH ? (i1 < 4 ? 1 : 2) : 0) * 3 + (bW ? (j1 < 4 ? 1 : 2) : 0);
                v = rpbt[((i1 - i2 + 6) * 13 + (j1 - j2 + 6)) * 12 + h];
                if (rn != rm) v -= 100.0f;
            } else {
                v = -1e30f;
            }
            outb[(ta * 4 + j) * 256 + t] = v;
        }
    }
}

// LN1 + cyclic shift(-3,-3) + window partition. One wave per output row.
__global__ __launch_bounds__(256) void ln1_window_k(const float* __restrict__ x,
                                                    const float* __restrict__ g,
                                                    const float* __restrict__ bta,
                                                    bf16* __restrict__ ywin) {
    int wrow = blockIdx.x * 4 + (threadIdx.x >> 6);
    int lane = threadIdx.x & 63;
    int tok = wrow % 49, win = wrow / 49;
    int i = tok / 7, j = tok % 7;
    int wwi = win & 7, whi = (win >> 3) & 7, bi = win >> 6;
    int hs = (whi * 7 + i + 3) % 56;
    int ws_ = (wwi * 7 + j + 3) % 56;
    const float* xr = x + ((size_t)bi * 3136 + (size_t)hs * 56 + ws_) * 384;
    float v[6]; float s = 0.f, s2 = 0.f;
#pragma unroll
    for (int u = 0; u < 6; ++u) { float t = xr[lane + 64 * u]; v[u] = t; s += t; s2 += t * t; }
#pragma unroll
    for (int d = 1; d < 64; d <<= 1) { s += __shfl_xor(s, d); s2 += __shfl_xor(s2, d); }
    float mean = s * (1.0f / 384.0f);
    float var = s2 * (1.0f / 384.0f) - mean * mean;
    float rstd = rsqrtf(var + 1e-5f);
    bf16* yr = ywin + (size_t)wrow * 384;
#pragma unroll
    for (int u = 0; u < 6; ++u) {
        int c = lane + 64 * u;
        yr[c] = __float2bfloat16((v[u] - mean) * rstd * g[c] + bta[c]);
    }
}

// residual add (window-reverse + roll(+3,+3)) + LN2. x2 -> d_out (fp32), z -> bf16
__global__ __launch_bounds__(256) void resid_ln2_k(const float* __restrict__ x,
                                                   const bf16* __restrict__ proj,
                                                   const float* __restrict__ g,
                                                   const float* __restrict__ bta,
                                                   float* __restrict__ x2,
                                                   bf16* __restrict__ z) {
    int row = blockIdx.x * 4 + (threadIdx.x >> 6);
    int lane = threadIdx.x & 63;
    int bi = row / 3136; int hw = row % 3136;
    int h = hw / 56, w = hw % 56;
    int h2 = (h + 53) % 56, w2 = (w + 53) % 56;
    int prow = ((bi * 8 + h2 / 7) * 8 + w2 / 7) * 49 + (h2 % 7) * 7 + (w2 % 7);
    const float* xr = x + (size_t)row * 384;
    const bf16* pr = proj + (size_t)prow * 384;
    float* x2r = x2 + (size_t)row * 384;
    float v[6]; float s = 0.f, s2 = 0.f;
#pragma unroll
    for (int u = 0; u < 6; ++u) {
        int c = lane + 64 * u;
        float t = xr[c] + __bfloat162float(pr[c]);
        v[u] = t; s += t; s2 += t * t;
        x2r[c] = t;
    }
#pragma unroll
    for (int d = 1; d < 64; d <<= 1) { s += __shfl_xor(s, d); s2 += __shfl_xor(s2, d); }
    float mean = s * (1.0f / 384.0f);
    float var = s2 * (1.0f / 384.0f) - mean * mean;
    float rstd = rsqrtf(var + 1e-5f);
    bf16* zr = z + (size_t)row * 384;
#pragma unroll
    for (int u = 0; u < 6; ++u) {
        int c = lane + 64 * u;
        zr[c] = __float2bfloat16((v[u] - mean) * rstd * g[c] + bta[c]);
    }
}

// MFMA windowed attention: grid (2048 windows, 3 head-groups); 4 waves,
// one wave per head; barrier-free; precomputed fragment-layout bias.
__global__ __launch_bounds__(256) void attn_mfma_k(const bf16* __restrict__ qkv,
                                                   const float* __restrict__ biasf,
                                                   bf16* __restrict__ o) {
    __shared__ __align__(16) __bf16 vt_s[4][32 * 72];   // V^T  [d][m], m padded to 64
    __shared__ __align__(16) __bf16 p_s[4][32 * 72];    // P half [n_loc][m]
    const int win = blockIdx.x;
    const int r = blockIdx.y;
    const int wave = threadIdx.x >> 6, lane = threadIdx.x & 63;
    const int lo = lane & 15, hi = lane >> 4;
    const int whi = (win >> 3) & 7, wwi = win & 7;
    const int wt = ((whi == 7) ? 2 : 0) + ((wwi == 7) ? 1 : 0);
    __bf16* vt_w = vt_s[wave];
    __bf16* p_w = p_s[wave];
    const int h = r * 4 + wave;
    const bf16* qbase = qkv + (size_t)win * 49 * 1152 + h * 32;
    const float* btile = biasf + (size_t)(wt * 12 + h) * 4096;
    bf16x8 zf = {};

    // V -> LDS transposed; lane handles column m
    {
        int m = lane;
        bf16x8 vrow[4];
#pragma unroll
        for (int d8 = 0; d8 < 4; ++d8)
            vrow[d8] = (m < 49) ? *(const bf16x8*)(qbase + (size_t)m * 1152 + 768 + d8 * 8) : zf;
#pragma unroll
        for (int d8 = 0; d8 < 4; ++d8)
#pragma unroll
            for (int e = 0; e < 8; ++e)
                vt_w[(d8 * 8 + e) * 72 + m] = vrow[d8][e];
    }
    bf16x8 aq[4], bk[4];
    const int kq = hi * 8;
#pragma unroll
    for (int ta = 0; ta < 4; ++ta) {
        int n = ta * 16 + lo;
        aq[ta] = (n < 49) ? *(const bf16x8*)(qbase + (size_t)n * 1152 + kq) : zf;
        bk[ta] = (n < 49) ? *(const bf16x8*)(qbase + (size_t)n * 1152 + 384 + kq) : zf;
    }
    f32x4 acc[4][4] = {};
#pragma unroll
    for (int ta = 0; ta < 4; ++ta)
#pragma unroll
        for (int tb = 0; tb < 4; ++tb)
            acc[ta][tb] = __builtin_amdgcn_mfma_f32_16x16x32_bf16(aq[ta], bk[tb], acc[ta][tb], 0, 0, 0);
#pragma unroll
    for (int ta = 0; ta < 4; ++ta) {
#pragma unroll
        for (int j = 0; j < 4; ++j) {
            float4 b4 = *(const float4*)(btile + (ta * 4 + j) * 256 + lane * 4);
            acc[ta][0][j] = fmaf(acc[ta][0][j], 0.17677669529663687f, b4.x);
            acc[ta][1][j] = fmaf(acc[ta][1][j], 0.17677669529663687f, b4.y);
            acc[ta][2][j] = fmaf(acc[ta][2][j], 0.17677669529663687f, b4.z);
            acc[ta][3][j] = fmaf(acc[ta][3][j], 0.17677669529663687f, b4.w);
        }
    }
    bf16x8 vb[2][2];
#pragma unroll
    for (int kb = 0; kb < 2; ++kb)
#pragma unroll
        for (int tb = 0; tb < 2; ++tb)
            vb[kb][tb] = *(const bf16x8*)(vt_w + (tb * 16 + lo) * 72 + kb * 32 + hi * 8);

    f32x4 oacc[4][2] = {};
#pragma unroll
    for (int half = 0; half < 2; ++half) {
#pragma unroll
        for (int tq = 0; tq < 2; ++tq) {
            int ta = half * 2 + tq;
#pragma unroll
            for (int j = 0; j < 4; ++j) {
                float mx = fmaxf(fmaxf(acc[ta][0][j], acc[ta][1][j]),
                                 fmaxf(acc[ta][2][j], acc[ta][3][j]));
                mx = fmaxf(mx, __shfl_xor(mx, 1));
                mx = fmaxf(mx, __shfl_xor(mx, 2));
                mx = fmaxf(mx, __shfl_xor(mx, 4));
                mx = fmaxf(mx, __shfl_xor(mx, 8));
                float e0 = __expf(acc[ta][0][j] - mx);
                float e1 = __expf(acc[ta][1][j] - mx);
                float e2 = __expf(acc[ta][2][j] - mx);
                float e3 = __expf(acc[ta][3][j] - mx);
                float sm = e0 + e1 + e2 + e3;
                sm += __shfl_xor(sm, 1);
                sm += __shfl_xor(sm, 2);
                sm += __shfl_xor(sm, 4);
                sm += __shfl_xor(sm, 8);
                float inv = 1.0f / sm;
                int nl = tq * 16 + hi * 4 + j;
                p_w[nl * 72 + lo]      = (__bf16)(e0 * inv);
                p_w[nl * 72 + 16 + lo] = (__bf16)(e1 * inv);
                p_w[nl * 72 + 32 + lo] = (__bf16)(e2 * inv);
                p_w[nl * 72 + 48 + lo] = (__bf16)(e3 * inv);
            }
        }
#pragma unroll
        for (int kb = 0; kb < 2; ++kb) {
#pragma unroll
            for (int tq = 0; tq < 2; ++tq) {
                bf16x8 pa = *(const bf16x8*)(p_w + (tq * 16 + lo) * 72 + kb * 32 + hi * 8);
#pragma unroll
                for (int tb = 0; tb < 2; ++tb)
                    oacc[half * 2 + tq][tb] =
                        __builtin_amdgcn_mfma_f32_16x16x32_bf16(pa, vb[kb][tb], oacc[half * 2 + tq][tb], 0, 0, 0);
            }
        }
    }
    bf16* obase = o + (size_t)win * 49 * 384 + h * 32;
#pragma unroll
    for (int ta = 0; ta < 4; ++ta) {
#pragma unroll
        for (int j = 0; j < 4; ++j) {
            int n = ta * 16 + hi * 4 + j;
            if (n < 49) {
#pragma unroll
                for (int tb = 0; tb < 2; ++tb)
                    obase[(size_t)n * 384 + tb * 16 + lo] = __float2bfloat16(oacc[ta][tb][j]);
            }
        }
    }
}

// C[M,N] = A[M,K] bf16 @ W[N,K]^T bf16.  K and N compile-time.
// VALU surgery: all in-loop ds_read addresses are 4 thread-const base
// pointers + compile-time immediates (row&7 == fr&7 since row offsets are
// multiples of 8 -> slot XOR is thread-const per ks). Epilogue uses one
// hoisted size_t base + constant strides (N is a template arg).
// WN=2: 256 thr 128x64 24KB; WN=4: 512 thr 128x128 32KB (32 waves/CU cap).
template <int K, int N, int WN, int EPI>
__global__ __launch_bounds__(WN * 128, 8 - WN) void gemm_bt(const bf16* __restrict__ A,
                                                            const bf16* __restrict__ W,
                                                            const float* __restrict__ bias,
                                                            void* __restrict__ Cout) {
    constexpr int T = WN * 128;
    constexpr int BN = WN * 32;
    __shared__ __align__(16) bf16 lds_a[128 * 64];
    __shared__ __align__(16) bf16 lds_b[BN * 64];
    const int t = threadIdx.x;
    const int wave = t >> 6, lane = t & 63;
    const int gdx = gridDim.x;
    int flat = blockIdx.y * gdx + blockIdx.x;
    int q = (gdx * gridDim.y) >> 3;
    int work = (flat & 7) * q + (flat >> 3);
    const int n0 = (work % gdx) * BN, m0 = (work / gdx) * 128;
    const int wm = wave / WN, wn = wave % WN;
    const int fr = lane & 15, hi = lane >> 4;
    // hoisted staging addresses (unit u = i*T + t; row = u>>3, slot = u&7)
    const int srow = t >> 3;
    const int gslot = (t & 7) ^ (srow & 7);
    const bf16* abase = A + (size_t)(m0 + srow) * K + gslot * 8;
    const bf16* bbase = W + (size_t)(n0 + srow) * K + gslot * 8;
    char* la = (char*)lds_a + t * 16;
    char* lb = (char*)lds_b + t * 16;
    // hoisted LDS read bases: addr(mi,ks) = base(ks) + mi*2048
    const int fp = fr & 7;
    const char* ra0 = (const char*)lds_a + (wm * 64 + fr) * 128 + (hi ^ fp) * 16;
    const char* ra1 = (const char*)lds_a + (wm * 64 + fr) * 128 + ((4 + hi) ^ fp) * 16;
    const char* rb0 = (const char*)lds_b + (wn * 32 + fr) * 128 + (hi ^ fp) * 16;
    const char* rb1 = (const char*)lds_b + (wn * 32 + fr) * 128 + ((4 + hi) ^ fp) * 16;
    f32x4 acc[4][2] = {};
#pragma unroll
    for (int kt = 0; kt < K; kt += 64) {
        if (kt > 0) __syncthreads();
#pragma unroll
        for (int i = 0; i < 1024 / T; ++i)
            async16(la + i * T * 16, abase + (size_t)i * (T >> 3) * K + kt);
#pragma unroll
        for (int i = 0; i < BN * 8 / T; ++i)
            async16(lb + i * T * 16, bbase + (size_t)i * (T >> 3) * K + kt);
        __syncthreads();
        bf16x8 af[4], bfr[2];
#pragma unroll
        for (int mi = 0; mi < 4; ++mi) af[mi] = *(const bf16x8*)(ra0 + mi * 2048);
#pragma unroll
        for (int ni = 0; ni < 2; ++ni) bfr[ni] = *(const bf16x8*)(rb0 + ni * 2048);
#pragma unroll
        for (int mi = 0; mi < 4; ++mi)
#pragma unroll
            for (int ni = 0; ni < 2; ++ni)
                acc[mi][ni] = __builtin_amdgcn_mfma_f32_16x16x32_bf16(bfr[ni], af[mi], acc[mi][ni], 0, 0, 0);
#pragma unroll
        for (int mi = 0; mi < 4; ++mi) af[mi] = *(const bf16x8*)(ra1 + mi * 2048);
#pragma unroll
        for (int ni = 0; ni < 2; ++ni) bfr[ni] = *(const bf16x8*)(rb1 + ni * 2048);
#pragma unroll
        for (int mi = 0; mi < 4; ++mi)
#pragma unroll
            for (int ni = 0; ni < 2; ++ni)
                acc[mi][ni] = __builtin_amdgcn_mfma_f32_16x16x32_bf16(bfr[ni], af[mi], acc[mi][ni], 0, 0, 0);
    }
    const int rq4 = hi * 4;
    const int ncol = n0 + wn * 32 + rq4;
    const size_t cbase = (size_t)(m0 + wm * 64 + fr) * N + ncol;
    const float* pb = bias ? bias + ncol : nullptr;
#pragma unroll
    for (int mi = 0; mi < 4; ++mi) {
#pragma unroll
        for (int ni = 0; ni < 2; ++ni) {
            float v0 = acc[mi][ni][0], v1 = acc[mi][ni][1];
            float v2 = acc[mi][ni][2], v3 = acc[mi][ni][3];
            if (pb) {
                float4 b4 = *(const float4*)(pb + ni * 16);
                v0 += b4.x; v1 += b4.y; v2 += b4.z; v3 += b4.w;
            }
            if (EPI == 1) { v0 = gelu_f(v0); v1 = gelu_f(v1); v2 = gelu_f(v2); v3 = gelu_f(v3); }
            if (EPI == 2) {
                float4* p = (float4*)((float*)Cout + cbase + (size_t)mi * 16 * N + ni * 16);
                float4 o = *p;
                o.x += v0; o.y += v1; o.z += v2; o.w += v3;
                *p = o;
            } else {
                bf16x4v st = { (__bf16)v0, (__bf16)v1, (__bf16)v2, (__bf16)v3 };
                *(bf16x4v*)((bf16*)Cout + cbase + (size_t)mi * 16 * N + ni * 16) = st;
            }
        }
    }
}

extern "C" void kernel_launch(void* const* d_in, const int* in_sizes, int n_in,
                              void* d_out, int out_size, void* d_ws, size_t ws_size,
                              hipStream_t stream) {
    const float* x      = (const float*)d_in[0];
    const float* n1g    = (const float*)d_in[1];
    const float* n1b    = (const float*)d_in[2];
    const float* rpbt   = (const float*)d_in[3];
    const float* qkv_v  = (const float*)d_in[4];
    const float* qkv_u  = (const float*)d_in[5];
    const float* qkv_b  = (const float*)d_in[6];
    const float* proj_v = (const float*)d_in[7];
    const float* proj_u = (const float*)d_in[8];
    const float* proj_b = (const float*)d_in[9];
    const float* n2g    = (const float*)d_in[10];
    const float* n2b    = (const float*)d_in[11];
    const float* fc1_v  = (const float*)d_in[12];
    const float* fc1_u  = (const float*)d_in[13];
    const float* fc1_b  = (const float*)d_in[14];
    const float* fc2_v  = (const float*)d_in[15];
    const float* fc2_u  = (const float*)d_in[16];
    const float* fc2_b  = (const float*)d_in[17];

    char* ws = (char*)d_ws;
    bf16* wb = (bf16*)ws;
    bf16* w_qkv_v  = wb;
    bf16* w_qkv_u  = wb + 73728;
    bf16* w_proj_v = wb + 294912;
    bf16* w_proj_u = wb + 368640;
    bf16* w_fc1_v  = wb + 442368;
    bf16* w_fc1_u  = wb + 516096;
    bf16* w_fc2_v  = wb + 811008;
    bf16* w_fc2_u  = wb + 1105920;
    float* biasf   = (float*)(ws + 3145728);   // 768 KB, ends < 4 MB
    size_t off = (size_t)4 << 20;
    bf16* R1 = (bf16*)(ws + off); off += (size_t)MROWS * 1536 * 2;   // qkv / proj / mlp-hidden
    bf16* R2 = (bf16*)(ws + off); off += (size_t)MROWS * 384 * 2;    // ywin / o / z
    bf16* R3 = (bf16*)(ws + off);                                    // t1/t2/t3/t4 (M x 192)
    float* out = (float*)d_out;

    Cvt8 c;
    c.s[0] = qkv_v;  c.d[0] = w_qkv_v;  c.n[0] = 73728;
    c.s[1] = qkv_u;  c.d[1] = w_qkv_u;  c.n[1] = 221184;
    c.s[2] = proj_v; c.d[2] = w_proj_v; c.n[2] = 73728;
    c.s[3] = proj_u; c.d[3] = w_proj_u; c.n[3] = 73728;
    c.s[4] = fc1_v;  c.d[4] = w_fc1_v;  c.n[4] = 73728;
    c.s[5] = fc1_u;  c.d[5] = w_fc1_u;  c.n[5] = 294912;
    c.s[6] = fc2_v;  c.d[6] = w_fc2_v;  c.n[6] = 294912;
    c.s[7] = fc2_u;  c.d[7] = w_fc2_u;  c.n[7] = 73728;
    cvt8_k<<<dim3(288, 8), 256, 0, stream>>>(c);
    bias_pre_k<<<48, 256, 0, stream>>>(rpbt, biasf);

    ln1_window_k<<<MROWS / 4, 256, 0, stream>>>(x, n1g, n1b, R2);
    gemm_bt<384, 192, 2, 0><<<dim3(3, 784), 256, 0, stream>>>(R2, w_qkv_v, nullptr, R3);
    gemm_bt<192, 1152, 4, 0><<<dim3(9, 784), 512, 0, stream>>>(R3, w_qkv_u, qkv_b, R1);
    attn_mfma_k<<<dim3(2048, 3), 256, 0, stream>>>(R1, biasf, R2);
    gemm_bt<384, 192, 2, 0><<<dim3(3, 784), 256, 0, stream>>>(R2, w_proj_v, nullptr, R3);
    gemm_bt<192, 384, 4, 0><<<dim3(3, 784), 512, 0, stream>>>(R3, w_proj_u, proj_b, R1);
    resid_ln2_k<<<MROWS / 4, 256, 0, stream>>>(x, R1, n2g, n2b, out, R2);
    gemm_bt<384, 192, 2, 0><<<dim3(3, 784), 256, 0, stream>>>(R2, w_fc1_v, nullptr, R3);
    gemm_bt<192, 1536, 4, 1><<<dim3(12, 784), 512, 0, stream>>>(R3, w_fc1_u, fc1_b, R1);
    gemm_bt<1536, 192, 2, 0><<<dim3(3, 784), 256, 0, stream>>>(R1, w_fc2_v, nullptr, R3);
    gemm_bt<192, 384, 4, 2><<<dim3(3, 784), 512, 0, stream>>>(R3, w_fc2_u, fc2_b, out);
}